// Round 5
// baseline (217.821 us; speedup 1.0000x reference)
//
#include <hip/hip_runtime.h>
#include <hip/hip_bf16.h>
#include <stdint.h>

#define HD 128
#define NB 8
#define TQN 512
#define TKN 512
#define QT 16       // queries per block
#define KTILE 64
#define KSTR 129    // kp_s row stride: (129k+h)%32 -> 2-way bank aliasing (free)

typedef __attribute__((ext_vector_type(8))) short short8;  // 8 bf16 (4 VGPRs)
typedef __attribute__((ext_vector_type(4))) float f32x4;   // MFMA C/D

static __device__ __forceinline__ float lo16(uint32_t w){
  union { uint32_t i; float f; } v; v.i = w << 16; return v.f;
}
static __device__ __forceinline__ float hi16(uint32_t w){
  union { uint32_t i; float f; } v; v.i = w & 0xffff0000u; return v.f;
}
static __device__ __forceinline__ float bf2f(unsigned short u){
  union { uint32_t i; float f; } v; v.i = ((uint32_t)u) << 16; return v.f;
}
static __device__ __forceinline__ uint32_t f2bf(float f){   // RNE
  union { float f; uint32_t i; } v; v.f = f;
  uint32_t u = v.i;
  u += 0x7fffu + ((u >> 16) & 1u);
  return u >> 16;
}

// load 1 element as float; load 8 consecutive elements as bf16 fragment.
static __device__ __forceinline__ float ld1(const void* p, size_t idx, bool f32){
  return f32 ? ((const float*)p)[idx] : bf2f(((const unsigned short*)p)[idx]);
}
static __device__ __forceinline__ short8 ld8bf(const void* p, size_t idx, bool f32){
  short8 r;
  if (f32){
    const float* s = (const float*)p + idx;
    #pragma unroll
    for (int i = 0; i < 8; i++) r[i] = (short)f2bf(s[i]);
  } else {
    r = *(const short8*)((const unsigned short*)p + idx);
  }
  return r;
}

// One block = (batch, 16-query tile). Fully self-sufficient single dispatch:
// projections recomputed per block via MFMA; per-input dtype detected by an
// inlined probe (fp32 data seen as ushort pairs has random high exponent-field
// bytes in the low halves; bf16 data |x|<~5 never has exp-field > 0x90).
__global__ __launch_bounds__(256, 2) void fused_kernel(
    const void* __restrict__ queries, const void* __restrict__ keys,
    const void* __restrict__ Wa_w,   const void* __restrict__ Wa_b,
    const void* __restrict__ Ua_w,   const void* __restrict__ Ua_b,
    const void* __restrict__ Va_w,
    void* __restrict__ out)
{
  __shared__ float qp_s[QT*HD];                     // 8 KB, pre-scaled by 2log2e
  __shared__ float va_s[HD];                        // 0.5 KB
  __shared__ __align__(16) float kp_s[KTILE*KSTR];  // 32.25 KB (phase-3: fp32 key stage)
  __shared__ float sc_s[QT*TKN];                    // 32 KB (scores -> fp32 weights)
  __shared__ unsigned int flg_s[8];

  const int tid  = threadIdx.x;

  // ---- inlined dtype probe (per block; L2-cached after first block) ----
  if (tid < 8) flg_s[tid] = 0;
  __syncthreads();
  {
    const void* ptrs[7] = {queries, keys, Wa_w, Wa_b, Ua_w, Ua_b, Va_w};
    const int grp = tid >> 5;           // 0..7; inputs 0..6 (Va_b ignored)
    const int l   = tid & 31;
    if (grp < 7){
      const unsigned short* p = (const unsigned short*)ptrs[grp];
      unsigned short a = p[2*l];        // every input has >=128 elements
      unsigned short c = p[64 + 2*l];
      if (((a >> 7) & 0xFF) > 0x90 || ((c >> 7) & 0xFF) > 0x90)
        atomicOr(&flg_s[grp], 1u);
    }
  }
  __syncthreads();
  const bool fQ  = flg_s[0] != 0;   // also selects OUTPUT dtype
  const bool fK  = flg_s[1] != 0;
  const bool fWw = flg_s[2] != 0;
  const bool fWb = flg_s[3] != 0;
  const bool fUw = flg_s[4] != 0;
  const bool fUb = flg_s[5] != 0;
  const bool fVw = flg_s[6] != 0;
  // Va_b deliberately unused: constant score shift, softmax-invariant.

  const int lane = tid & 63;
  const int wv   = tid >> 6;        // wave 0..3
  const int ln   = lane & 15;
  const int quad = lane >> 4;
  const int b     = blockIdx.x >> 5;
  const int qbase = (blockIdx.x & 31) * QT;
  const float Cs = 2.8853900817779268f;  // 2*log2(e): tanh arg feeds exp2 directly

  if (tid < HD) va_s[tid] = ld1(Va_w, tid, fVw);

  // ---- qp tile via MFMA: (16q x 128h) = queries_tile @ Wa^T + b, scaled ----
  {
    const size_t qa = (size_t)(b*TQN + qbase + ln)*HD + quad*8;
    short8 a0 = ld8bf(queries, qa,      fQ);
    short8 a1 = ld8bf(queries, qa + 32, fQ);
    short8 a2 = ld8bf(queries, qa + 64, fQ);
    short8 a3 = ld8bf(queries, qa + 96, fQ);
    #pragma unroll
    for (int nt = 0; nt < 2; nt++){
      const int h0 = (2*wv + nt)*16;
      const size_t wp = (size_t)(h0 + ln)*HD + quad*8;
      f32x4 c = {0.f,0.f,0.f,0.f};
      c = __builtin_amdgcn_mfma_f32_16x16x32_bf16(a0, ld8bf(Wa_w, wp,      fWw), c, 0,0,0);
      c = __builtin_amdgcn_mfma_f32_16x16x32_bf16(a1, ld8bf(Wa_w, wp + 32, fWw), c, 0,0,0);
      c = __builtin_amdgcn_mfma_f32_16x16x32_bf16(a2, ld8bf(Wa_w, wp + 64, fWw), c, 0,0,0);
      c = __builtin_amdgcn_mfma_f32_16x16x32_bf16(a3, ld8bf(Wa_w, wp + 96, fWw), c, 0,0,0);
      const float wb = ld1(Wa_b, h0 + ln, fWb);
      #pragma unroll
      for (int r = 0; r < 4; r++)   // D: col=lane&15, row=quad*4+r (m89/m91)
        qp_s[(quad*4 + r)*HD + h0 + ln] = (c[r] + wb)*Cs;
    }
  }

  // ---- hoist Ua B-frags (B[k=quad*8+j][n=lane&15]) for this wave's n-tiles ----
  short8 ub[2][4];
  float ubias[2];
  #pragma unroll
  for (int nt = 0; nt < 2; nt++){
    const int h0 = (2*wv + nt)*16;
    #pragma unroll
    for (int ks = 0; ks < 4; ks++)
      ub[nt][ks] = ld8bf(Ua_w, (size_t)(h0 + ln)*HD + quad*8 + ks*32, fUw);
    ubias[nt] = ld1(Ua_b, h0 + ln, fUb);
  }

  __syncthreads();   // qp_s, va_s complete

  // S0 = sum(Va)  (score-sans-Va_b = S0 - 2*sum(Va_h * r_h), r = 1/(1+e^{2x}))
  float S0 = 0.f;
  #pragma unroll 8
  for (int h = 0; h < HD; h++) S0 += va_s[h];

  const float* qr0 = qp_s + (wv     )*HD;   // wave-uniform -> LDS broadcast
  const float* qr1 = qp_s + (wv +  4)*HD;
  const float* qr2 = qp_s + (wv +  8)*HD;
  const float* qr3 = qp_s + (wv + 12)*HD;

  // ======== main loop over 8 key tiles ========
  for (int kt = 0; kt < 8; kt++){
    // -- recompute kp tile (64k x 128h) via MFMA: keys_tile @ Ua^T + b --
    f32x4 kc[4][2];
    #pragma unroll
    for (int mt = 0; mt < 4; mt++)
      #pragma unroll
      for (int nt = 0; nt < 2; nt++) kc[mt][nt] = (f32x4){0.f,0.f,0.f,0.f};
    #pragma unroll
    for (int ks = 0; ks < 4; ks++){
      short8 af[4];
      #pragma unroll
      for (int mt = 0; mt < 4; mt++)
        af[mt] = ld8bf(keys, (size_t)(b*TKN + kt*KTILE + mt*16 + ln)*HD + ks*32 + quad*8, fK);
      #pragma unroll
      for (int mt = 0; mt < 4; mt++)
        #pragma unroll
        for (int nt = 0; nt < 2; nt++)
          kc[mt][nt] = __builtin_amdgcn_mfma_f32_16x16x32_bf16(af[mt], ub[nt][ks], kc[mt][nt], 0,0,0);
    }
    #pragma unroll
    for (int mt = 0; mt < 4; mt++)
      #pragma unroll
      for (int nt = 0; nt < 2; nt++){
        const int h0 = (2*wv + nt)*16;
        #pragma unroll
        for (int r = 0; r < 4; r++)
          kp_s[(mt*16 + quad*4 + r)*KSTR + h0 + ln] = (kc[mt][nt][r] + ubias[nt])*Cs;
      }
    __syncthreads();   // kp tile complete

    // -- phase 1: 64 keys x 4 queries per thread --
    float ac0=0.f, ac1=0.f, ac2=0.f, ac3=0.f;
    const float* krow = kp_s + lane*KSTR;
    #pragma unroll 4
    for (int h = 0; h < HD; h++){
      const float kv = krow[h];
      const float va = va_s[h];
      const float r0 = __builtin_amdgcn_rcpf(__builtin_amdgcn_exp2f(qr0[h] + kv) + 1.f);
      const float r1 = __builtin_amdgcn_rcpf(__builtin_amdgcn_exp2f(qr1[h] + kv) + 1.f);
      const float r2 = __builtin_amdgcn_rcpf(__builtin_amdgcn_exp2f(qr2[h] + kv) + 1.f);
      const float r3 = __builtin_amdgcn_rcpf(__builtin_amdgcn_exp2f(qr3[h] + kv) + 1.f);
      ac0 = fmaf(va, r0, ac0); ac1 = fmaf(va, r1, ac1);
      ac2 = fmaf(va, r2, ac2); ac3 = fmaf(va, r3, ac3);
    }
    const int kg = kt*KTILE + lane;
    sc_s[(wv     )*TKN + kg] = S0 - 2.f*ac0;
    sc_s[(wv +  4)*TKN + kg] = S0 - 2.f*ac1;
    sc_s[(wv +  8)*TKN + kg] = S0 - 2.f*ac2;
    sc_s[(wv + 12)*TKN + kg] = S0 - 2.f*ac3;
    __syncthreads();
  }

  // ======== softmax over 512 keys; 16 threads per query row ========
  {
    const int q = tid >> 4;
    const int l = tid & 15;
    float vals[32];
    float m = -1e30f;
    #pragma unroll
    for (int j = 0; j < 32; j++){
      vals[j] = sc_s[q*TKN + l + 16*j];
      m = fmaxf(m, vals[j]);
    }
    #pragma unroll
    for (int o = 8; o > 0; o >>= 1) m = fmaxf(m, __shfl_xor(m, o));
    float sum = 0.f;
    #pragma unroll
    for (int j = 0; j < 32; j++){
      vals[j] = __builtin_amdgcn_exp2f((vals[j]-m)*1.4426950408889634f);
      sum += vals[j];
    }
    #pragma unroll
    for (int o = 8; o > 0; o >>= 1) sum += __shfl_xor(sum, o);
    const float inv = 1.f / sum;
    const size_t wbase = (size_t)NB*TQN*HD + (size_t)(b*TQN + qbase + q)*TKN;
    #pragma unroll
    for (int j = 0; j < 32; j++){
      const float w = vals[j]*inv;
      sc_s[q*TKN + l + 16*j] = w;              // fp32 weights for phase 3
      if (fQ) ((float*)out)[wbase + l + 16*j] = w;
      else    ((unsigned short*)out)[wbase + l + 16*j] = (unsigned short)f2bf(w);
    }
  }
  __syncthreads();

  // ======== phase 3: contexts = weights @ keys, keys staged fp32 in LDS ====
  {
    const int q  = tid >> 4;
    const int h0 = (tid & 15) * 8;
    float a0=0.f,a1=0.f,a2=0.f,a3=0.f,a4=0.f,a5=0.f,a6=0.f,a7=0.f;
    float* ks_f = kp_s;   // reuse dead kp_s: 64*128 fp32 = 32 KB <= 32.25 KB
    for (int kt = 0; kt < 8; kt++){
      if (fK){
        const float4* src = (const float4*)((const float*)keys + (size_t)(b*TKN + kt*KTILE)*HD);
        float4* dst = (float4*)ks_f;
        #pragma unroll
        for (int j = 0; j < 8; j++) dst[tid + 256*j] = src[tid + 256*j];
      } else {
        const uint4* src = (const uint4*)((const unsigned short*)keys + (size_t)(b*TKN + kt*KTILE)*HD);
        float4* dst = (float4*)ks_f;
        #pragma unroll
        for (int j = 0; j < 4; j++){
          const int f = tid + 256*j;
          uint4 v = src[f];
          float4 d0, d1;
          d0.x = lo16(v.x); d0.y = hi16(v.x); d0.z = lo16(v.y); d0.w = hi16(v.y);
          d1.x = lo16(v.z); d1.y = hi16(v.z); d1.z = lo16(v.w); d1.w = hi16(v.w);
          dst[2*f]   = d0;
          dst[2*f+1] = d1;
        }
      }
      __syncthreads();
      const float* wr = sc_s + q*TKN + kt*KTILE;
      #pragma unroll 2
      for (int k = 0; k < KTILE; k++){
        const float w = wr[k];
        const float4 k0 = *(const float4*)(ks_f + k*HD + h0);
        const float4 k1 = *(const float4*)(ks_f + k*HD + h0 + 4);
        a0 = fmaf(w, k0.x, a0); a1 = fmaf(w, k0.y, a1);
        a2 = fmaf(w, k0.z, a2); a3 = fmaf(w, k0.w, a3);
        a4 = fmaf(w, k1.x, a4); a5 = fmaf(w, k1.y, a5);
        a6 = fmaf(w, k1.z, a6); a7 = fmaf(w, k1.w, a7);
      }
      __syncthreads();
    }
    const size_t crow = (size_t)(b*TQN + qbase + q)*HD + h0;
    if (fQ){
      float* oc = (float*)out;
      *(float4*)(oc + crow)     = (float4){a0,a1,a2,a3};
      *(float4*)(oc + crow + 4) = (float4){a4,a5,a6,a7};
    } else {
      uint4 o;
      o.x = f2bf(a0) | (f2bf(a1) << 16);
      o.y = f2bf(a2) | (f2bf(a3) << 16);
      o.z = f2bf(a4) | (f2bf(a5) << 16);
      o.w = f2bf(a6) | (f2bf(a7) << 16);
      *(uint4*)((unsigned short*)out + crow) = o;
    }
  }
}

extern "C" void kernel_launch(void* const* d_in, const int* in_sizes, int n_in,
                              void* d_out, int out_size, void* d_ws, size_t ws_size,
                              hipStream_t stream) {
  (void)in_sizes; (void)n_in; (void)out_size; (void)d_ws; (void)ws_size;
  fused_kernel<<<256, 256, 0, stream>>>(d_in[0], d_in[1], d_in[2], d_in[3],
                                        d_in[4], d_in[5], d_in[6], d_out);
}

// Round 6
// 166.191 us; speedup vs baseline: 1.3107x; 1.3107x over previous
//
#include <hip/hip_runtime.h>
#include <hip/hip_bf16.h>
#include <stdint.h>

#define HD 128
#define NB 8
#define TQN 512
#define TKN 512
#define QT 8        // queries per block
#define KTILE 64
#define KSTR 132    // kp_s row stride (floats): b128-aligned, uniform bank groups
#define QSTR 132    // qp_s row stride (floats)
#define KBSTR 136   // keys_s row stride (bf16): 272 B -> (17*ln+quad)%8 uniform

typedef __attribute__((ext_vector_type(8))) short short8;  // 8 bf16 (4 VGPRs)
typedef __attribute__((ext_vector_type(4))) float f32x4;   // MFMA C/D

static __device__ __forceinline__ float lo16(uint32_t w){
  union { uint32_t i; float f; } v; v.i = w << 16; return v.f;
}
static __device__ __forceinline__ float hi16(uint32_t w){
  union { uint32_t i; float f; } v; v.i = w & 0xffff0000u; return v.f;
}
static __device__ __forceinline__ float bf2f(unsigned short u){
  union { uint32_t i; float f; } v; v.i = ((uint32_t)u) << 16; return v.f;
}
static __device__ __forceinline__ uint32_t f2bf(float f){   // RNE
  union { float f; uint32_t i; } v; v.f = f;
  uint32_t u = v.i;
  u += 0x7fffu + ((u >> 16) & 1u);
  return u >> 16;
}

// load 1 element as float; load 8 consecutive elements as bf16 fragment.
static __device__ __forceinline__ float ld1(const void* p, size_t idx, bool f32){
  return f32 ? ((const float*)p)[idx] : bf2f(((const unsigned short*)p)[idx]);
}
static __device__ __forceinline__ short8 ld8bf(const void* p, size_t idx, bool f32){
  short8 r;
  if (f32){
    const float* s = (const float*)p + idx;
    #pragma unroll
    for (int i = 0; i < 8; i++) r[i] = (short)f2bf(s[i]);
  } else {
    r = *(const short8*)((const unsigned short*)p + idx);
  }
  return r;
}

// stage 64x128 keys tile kt into LDS as bf16 (row stride KBSTR)
static __device__ __forceinline__ void stage_keys(const void* keys, bool fK,
    unsigned short* keys_s, int b, int kt, int tid){
  if (fK){
    const float4* src = (const float4*)((const float*)keys + (size_t)(b*TKN + kt*KTILE)*HD);
    #pragma unroll
    for (int j = 0; j < 4; j++){
      const int f = tid + 512*j;        // float4 index within tile
      float4 v = src[f];
      const int k = f >> 5;             // (f*4)/128
      const int h = (f & 31) * 4;
      uint2 p;
      p.x = f2bf(v.x) | (f2bf(v.y) << 16);
      p.y = f2bf(v.z) | (f2bf(v.w) << 16);
      *(uint2*)(keys_s + k*KBSTR + h) = p;
    }
  } else {
    const uint4* src = (const uint4*)((const unsigned short*)keys + (size_t)(b*TKN + kt*KTILE)*HD);
    #pragma unroll
    for (int j = 0; j < 2; j++){
      const int f = tid + 512*j;        // uint4 index (8 bf16)
      uint4 v = src[f];
      const int k = f >> 4;
      const int h = (f & 15) * 8;
      *(uint4*)(keys_s + k*KBSTR + h) = v;
    }
  }
}

// One block = (batch, 8-query tile); 512 blocks x 512 threads -> 16 waves/CU.
__global__ __launch_bounds__(512, 4) void fused_kernel(
    const void* __restrict__ queries, const void* __restrict__ keys,
    const void* __restrict__ Wa_w,   const void* __restrict__ Wa_b,
    const void* __restrict__ Ua_w,   const void* __restrict__ Ua_b,
    const void* __restrict__ Va_w,
    void* __restrict__ out)
{
  __shared__ float qp_s[QT*QSTR];                       // 4.2 KB (pre-scaled 2log2e)
  __shared__ float va_s[HD];                            // 0.5 KB
  __shared__ __align__(16) unsigned short keys_s[KTILE*KBSTR]; // 17 KB bf16 tile
  __shared__ __align__(16) float kp_s[KTILE*KSTR];      // 33 KB (phase3: fp32 keys)
  __shared__ float sc_s[QT*TKN];                        // 16 KB scores->weights
  __shared__ unsigned int flg_s[8];

  const int tid = threadIdx.x;

  // ---- inlined dtype probe ----
  if (tid < 8) flg_s[tid] = 0;
  __syncthreads();
  {
    const void* ptrs[7] = {queries, keys, Wa_w, Wa_b, Ua_w, Ua_b, Va_w};
    const int grp = tid >> 5;
    const int l   = tid & 31;
    if (grp < 7){
      const unsigned short* p = (const unsigned short*)ptrs[grp];
      unsigned short a = p[2*l];
      unsigned short c = p[64 + 2*l];
      if (((a >> 7) & 0xFF) > 0x90 || ((c >> 7) & 0xFF) > 0x90)
        atomicOr(&flg_s[grp], 1u);
    }
  }
  __syncthreads();
  const bool fQ  = flg_s[0] != 0;   // also selects OUTPUT dtype
  const bool fK  = flg_s[1] != 0;
  const bool fWw = flg_s[2] != 0;
  const bool fWb = flg_s[3] != 0;
  const bool fUw = flg_s[4] != 0;
  const bool fUb = flg_s[5] != 0;
  const bool fVw = flg_s[6] != 0;
  // Va_b unused: constant score shift, softmax-invariant.

  const int lane = tid & 63;
  const int wv   = tid >> 6;        // wave 0..7
  const int ln   = lane & 15;
  const int quad = lane >> 4;
  const int b     = blockIdx.x >> 6;
  const int qbase = (blockIdx.x & 63) * QT;
  const float Cs = 2.8853900817779268f;  // 2*log2(e)

  if (tid < HD) va_s[tid] = ld1(Va_w, tid, fVw);

  // ---- qp tile via MFMA: wave wv computes cols [16wv,16wv+16) ----
  {
    const int h0 = wv * 16;
    const size_t qrow = (size_t)(b*TQN + qbase + (ln & 7))*HD;  // rows 8..15 dup
    f32x4 c = {0.f,0.f,0.f,0.f};
    #pragma unroll
    for (int ks = 0; ks < 4; ks++){
      short8 a = ld8bf(queries, qrow + ks*32 + quad*8, fQ);
      short8 w = ld8bf(Wa_w, (size_t)(h0 + ln)*HD + ks*32 + quad*8, fWw);
      c = __builtin_amdgcn_mfma_f32_16x16x32_bf16(a, w, c, 0,0,0);
    }
    const float wb = ld1(Wa_b, h0 + ln, fWb);
    #pragma unroll
    for (int r = 0; r < 4; r++){      // D: col=ln, row=quad*4+r
      const int row = quad*4 + r;
      if (row < QT) qp_s[row*QSTR + h0 + ln] = (c[r] + wb)*Cs;
    }
  }

  // ---- hoist Ua B-frags for wave's n-tile (cols 16wv..16wv+15) ----
  short8 ub[4];
  float ubias;
  {
    const int h0 = wv * 16;
    #pragma unroll
    for (int ks = 0; ks < 4; ks++)
      ub[ks] = ld8bf(Ua_w, (size_t)(h0 + ln)*HD + ks*32 + quad*8, fUw);
    ubias = ld1(Ua_b, h0 + ln, fUb);
  }

  stage_keys(keys, fK, keys_s, b, 0, tid);
  __syncthreads();   // qp_s, va_s, keys_s(0) complete

  // S0 = sum(Va)
  float S0 = 0.f;
  #pragma unroll 8
  for (int h = 0; h < HD; h++) S0 += va_s[h];

  const float4* q4p = (const float4*)(qp_s + wv*QSTR);   // wave-uniform
  const float4* v4p = (const float4*)va_s;

  // ======== main loop: 8 key tiles, 2-barrier pipeline ========
  for (int kt = 0; kt < 8; kt++){
    // slot 1: kp MFMA reads keys_s -> regs (wave wv: n-tile = cols 16wv..+15)
    f32x4 kc[4];
    #pragma unroll
    for (int mt = 0; mt < 4; mt++) kc[mt] = (f32x4){0.f,0.f,0.f,0.f};
    #pragma unroll
    for (int ks = 0; ks < 4; ks++){
      short8 af[4];
      #pragma unroll
      for (int mt = 0; mt < 4; mt++)
        af[mt] = *(const short8*)(keys_s + (mt*16 + ln)*KBSTR + ks*32 + quad*8);
      #pragma unroll
      for (int mt = 0; mt < 4; mt++)
        kc[mt] = __builtin_amdgcn_mfma_f32_16x16x32_bf16(af[mt], ub[ks], kc[mt], 0,0,0);
    }
    __syncthreads();   // B1: keys_s reads + prev phase-1 kp_s reads complete

    // slot 2: write kp tile; stage next keys tile (disjoint LDS regions)
    #pragma unroll
    for (int mt = 0; mt < 4; mt++)
      #pragma unroll
      for (int r = 0; r < 4; r++)
        kp_s[(mt*16 + quad*4 + r)*KSTR + wv*16 + ln] = (kc[mt][r] + ubias)*Cs;
    if (kt < 7) stage_keys(keys, fK, keys_s, b, kt+1, tid);
    __syncthreads();   // B2

    // slot 3: phase 1 — thread = (q=wv, key=lane); b128 LDS reads
    float acc = 0.f;
    const float4* krow4 = (const float4*)(kp_s + lane*KSTR);
    #pragma unroll 8
    for (int hh = 0; hh < 32; hh++){
      const float4 kv = krow4[hh];
      const float4 qv = q4p[hh];
      const float4 vv = v4p[hh];
      float r0 = __builtin_amdgcn_rcpf(__builtin_amdgcn_exp2f(qv.x + kv.x) + 1.f);
      float r1 = __builtin_amdgcn_rcpf(__builtin_amdgcn_exp2f(qv.y + kv.y) + 1.f);
      float r2 = __builtin_amdgcn_rcpf(__builtin_amdgcn_exp2f(qv.z + kv.z) + 1.f);
      float r3 = __builtin_amdgcn_rcpf(__builtin_amdgcn_exp2f(qv.w + kv.w) + 1.f);
      acc = fmaf(vv.x, r0, acc);
      acc = fmaf(vv.y, r1, acc);
      acc = fmaf(vv.z, r2, acc);
      acc = fmaf(vv.w, r3, acc);
    }
    sc_s[wv*TKN + kt*KTILE + lane] = S0 - 2.f*acc;
    // no barrier: next slot-1 touches only keys_s (B2-protected)
  }
  __syncthreads();   // all scores visible

  // ======== softmax: wave wv owns query row wv; 64 lanes x 8 keys ========
  {
    float vals[8];
    float m = -1e30f;
    #pragma unroll
    for (int j = 0; j < 8; j++){
      vals[j] = sc_s[wv*TKN + lane + 64*j];
      m = fmaxf(m, vals[j]);
    }
    #pragma unroll
    for (int o = 32; o > 0; o >>= 1) m = fmaxf(m, __shfl_xor(m, o));
    float sum = 0.f;
    #pragma unroll
    for (int j = 0; j < 8; j++){
      vals[j] = __builtin_amdgcn_exp2f((vals[j]-m)*1.4426950408889634f);
      sum += vals[j];
    }
    #pragma unroll
    for (int o = 32; o > 0; o >>= 1) sum += __shfl_xor(sum, o);
    const float inv = 1.f / sum;
    const size_t wbase = (size_t)NB*TQN*HD + (size_t)(b*TQN + qbase + wv)*TKN;
    #pragma unroll
    for (int j = 0; j < 8; j++){
      const float w = vals[j]*inv;
      sc_s[wv*TKN + lane + 64*j] = w;
      if (fQ) ((float*)out)[wbase + lane + 64*j] = w;
      else    ((unsigned short*)out)[wbase + lane + 64*j] = (unsigned short)f2bf(w);
    }
  }
  __syncthreads();

  // ======== phase 3: contexts = weights @ keys ========
  // wave wv = query row; ln -> h0 = ln*8 (8 cols); quad -> keys k = 4i+quad
  {
    const int h0 = ln * 8;
    float a[8];
    #pragma unroll
    for (int t = 0; t < 8; t++) a[t] = 0.f;
    for (int kt = 0; kt < 8; kt++){
      if (fK){
        const float4* src = (const float4*)((const float*)keys + (size_t)(b*TKN + kt*KTILE)*HD);
        #pragma unroll
        for (int j = 0; j < 4; j++){
          const int f = tid + 512*j;
          const int k = f >> 5;
          const int h = (f & 31) * 4;
          *(float4*)(kp_s + k*KSTR + h) = src[f];
        }
      } else {
        const uint4* src = (const uint4*)((const unsigned short*)keys + (size_t)(b*TKN + kt*KTILE)*HD);
        #pragma unroll
        for (int j = 0; j < 2; j++){
          const int f = tid + 512*j;
          const int k = f >> 4;
          const int h = (f & 15) * 8;
          uint4 v = src[f];
          float4 d0, d1;
          d0.x = lo16(v.x); d0.y = hi16(v.x); d0.z = lo16(v.y); d0.w = hi16(v.y);
          d1.x = lo16(v.z); d1.y = hi16(v.z); d1.z = lo16(v.w); d1.w = hi16(v.w);
          *(float4*)(kp_s + k*KSTR + h)     = d0;
          *(float4*)(kp_s + k*KSTR + h + 4) = d1;
        }
      }
      __syncthreads();
      const float* wr = sc_s + wv*TKN + kt*KTILE;
      #pragma unroll 4
      for (int i = 0; i < 16; i++){
        const int k = 4*i + quad;
        const float w = wr[k];
        const float4 k0 = *(const float4*)(kp_s + k*KSTR + h0);
        const float4 k1 = *(const float4*)(kp_s + k*KSTR + h0 + 4);
        a[0] = fmaf(w, k0.x, a[0]); a[1] = fmaf(w, k0.y, a[1]);
        a[2] = fmaf(w, k0.z, a[2]); a[3] = fmaf(w, k0.w, a[3]);
        a[4] = fmaf(w, k1.x, a[4]); a[5] = fmaf(w, k1.y, a[5]);
        a[6] = fmaf(w, k1.z, a[6]); a[7] = fmaf(w, k1.w, a[7]);
      }
      __syncthreads();
    }
    // cross-quad reduce (k split over quads)
    #pragma unroll
    for (int t = 0; t < 8; t++){
      a[t] += __shfl_xor(a[t], 16);
      a[t] += __shfl_xor(a[t], 32);
    }
    if (quad == 0){
      const size_t crow = (size_t)(b*TQN + qbase + wv)*HD + h0;
      if (fQ){
        float* oc = (float*)out;
        *(float4*)(oc + crow)     = (float4){a[0],a[1],a[2],a[3]};
        *(float4*)(oc + crow + 4) = (float4){a[4],a[5],a[6],a[7]};
      } else {
        uint4 o;
        o.x = f2bf(a[0]) | (f2bf(a[1]) << 16);
        o.y = f2bf(a[2]) | (f2bf(a[3]) << 16);
        o.z = f2bf(a[4]) | (f2bf(a[5]) << 16);
        o.w = f2bf(a[6]) | (f2bf(a[7]) << 16);
        *(uint4*)((unsigned short*)out + crow) = o;
      }
    }
  }
}

extern "C" void kernel_launch(void* const* d_in, const int* in_sizes, int n_in,
                              void* d_out, int out_size, void* d_ws, size_t ws_size,
                              hipStream_t stream) {
  (void)in_sizes; (void)n_in; (void)out_size; (void)d_ws; (void)ws_size;
  fused_kernel<<<512, 512, 0, stream>>>(d_in[0], d_in[1], d_in[2], d_in[3],
                                        d_in[4], d_in[5], d_in[6], d_out);
}

// Round 7
// 164.453 us; speedup vs baseline: 1.3245x; 1.0106x over previous
//
#include <hip/hip_runtime.h>
#include <hip/hip_bf16.h>
#include <stdint.h>

#define HD 128
#define NB 8
#define TQN 512
#define TKN 512
#define QT 8        // queries per block
#define KTILE 64
#define KSTR 132    // kp_s row stride (floats): b128-aligned
#define QSTR 132    // qp_s row stride (floats)
#define KBSTR 136   // keys_s row stride (bf16)

typedef __attribute__((ext_vector_type(8))) short short8;  // 8 bf16 (4 VGPRs)
typedef __attribute__((ext_vector_type(4))) float f32x4;   // MFMA C/D

static __device__ __forceinline__ float lo16(uint32_t w){
  union { uint32_t i; float f; } v; v.i = w << 16; return v.f;
}
static __device__ __forceinline__ float hi16(uint32_t w){
  union { uint32_t i; float f; } v; v.i = w & 0xffff0000u; return v.f;
}
static __device__ __forceinline__ float bf2f(unsigned short u){
  union { uint32_t i; float f; } v; v.i = ((uint32_t)u) << 16; return v.f;
}
static __device__ __forceinline__ uint32_t f2bf(float f){   // RNE
  union { float f; uint32_t i; } v; v.f = f;
  uint32_t u = v.i;
  u += 0x7fffu + ((u >> 16) & 1u);
  return u >> 16;
}

// reciprocal: magic seed + 2 Newton steps. rel err ~1.4e-6. No trans pipe.
static __device__ __forceinline__ float fast_rcp(float d){
  union { float f; uint32_t i; } v; v.f = d;
  v.i = 0x7EF311C3u - v.i;
  float y = v.f;
  y = y * fmaf(-d, y, 2.0f);
  y = y * fmaf(-d, y, 2.0f);
  return y;
}

// accurate tanh: 1 exp2 (trans) + NR reciprocal. err ~3e-6.
static __device__ __forceinline__ float tanh_acc(float x){
  float e = __builtin_amdgcn_exp2f(x * 2.8853900817779268f);  // 2^(2x*log2e)
  return fmaf(-2.0f, fast_rcp(e + 1.0f), 1.0f);
}

// load 1 element as float; load 8 consecutive elements as bf16 fragment.
static __device__ __forceinline__ float ld1(const void* p, size_t idx, bool f32){
  return f32 ? ((const float*)p)[idx] : bf2f(((const unsigned short*)p)[idx]);
}
static __device__ __forceinline__ short8 ld8bf(const void* p, size_t idx, bool f32){
  short8 r;
  if (f32){
    const float* s = (const float*)p + idx;
    #pragma unroll
    for (int i = 0; i < 8; i++) r[i] = (short)f2bf(s[i]);
  } else {
    r = *(const short8*)((const unsigned short*)p + idx);
  }
  return r;
}

// stage 64x128 keys tile kt into LDS as bf16 (row stride KBSTR)
static __device__ __forceinline__ void stage_keys(const void* keys, bool fK,
    unsigned short* keys_s, int b, int kt, int tid){
  if (fK){
    const float4* src = (const float4*)((const float*)keys + (size_t)(b*TKN + kt*KTILE)*HD);
    #pragma unroll
    for (int j = 0; j < 4; j++){
      const int f = tid + 512*j;
      float4 v = src[f];
      const int k = f >> 5;
      const int h = (f & 31) * 4;
      uint2 p;
      p.x = f2bf(v.x) | (f2bf(v.y) << 16);
      p.y = f2bf(v.z) | (f2bf(v.w) << 16);
      *(uint2*)(keys_s + k*KBSTR + h) = p;
    }
  } else {
    const uint4* src = (const uint4*)((const unsigned short*)keys + (size_t)(b*TKN + kt*KTILE)*HD);
    #pragma unroll
    for (int j = 0; j < 2; j++){
      const int f = tid + 512*j;
      uint4 v = src[f];
      const int k = f >> 4;
      const int h = (f & 15) * 8;
      *(uint4*)(keys_s + k*KBSTR + h) = v;
    }
  }
}

// One block = (batch, 8-query tile); 512 blocks x 512 threads.
// Inner loop: tanh(q+k) = (tq+tk)/(1+tq*tk) with NR reciprocal -> zero trans.
__global__ __launch_bounds__(512, 4) void fused_kernel(
    const void* __restrict__ queries, const void* __restrict__ keys,
    const void* __restrict__ Wa_w,   const void* __restrict__ Wa_b,
    const void* __restrict__ Ua_w,   const void* __restrict__ Ua_b,
    const void* __restrict__ Va_w,
    void* __restrict__ out)
{
  __shared__ float qp_s[QT*QSTR];                       // tq: tanh(q-proj)
  __shared__ float va_s[HD];
  __shared__ __align__(16) unsigned short keys_s[KTILE*KBSTR]; // bf16 keys tile
  __shared__ __align__(16) float kp_s[KTILE*KSTR];      // tk (phase3: fp32 keys)
  __shared__ float sc_s[QT*TKN];                        // scores -> weights
  __shared__ unsigned int flg_s[8];

  const int tid = threadIdx.x;

  // ---- inlined dtype probe ----
  if (tid < 8) flg_s[tid] = 0;
  __syncthreads();
  {
    const void* ptrs[7] = {queries, keys, Wa_w, Wa_b, Ua_w, Ua_b, Va_w};
    const int grp = tid >> 5;
    const int l   = tid & 31;
    if (grp < 7){
      const unsigned short* p = (const unsigned short*)ptrs[grp];
      unsigned short a = p[2*l];
      unsigned short c = p[64 + 2*l];
      if (((a >> 7) & 0xFF) > 0x90 || ((c >> 7) & 0xFF) > 0x90)
        atomicOr(&flg_s[grp], 1u);
    }
  }
  __syncthreads();
  const bool fQ  = flg_s[0] != 0;   // also selects OUTPUT dtype
  const bool fK  = flg_s[1] != 0;
  const bool fWw = flg_s[2] != 0;
  const bool fWb = flg_s[3] != 0;
  const bool fUw = flg_s[4] != 0;
  const bool fUb = flg_s[5] != 0;
  const bool fVw = flg_s[6] != 0;
  // Va_b unused: constant score shift, softmax-invariant.

  const int lane = tid & 63;
  const int wv   = tid >> 6;        // wave 0..7
  const int ln   = lane & 15;
  const int quad = lane >> 4;
  const int b     = blockIdx.x >> 6;
  const int qbase = (blockIdx.x & 63) * QT;

  if (tid < HD) va_s[tid] = ld1(Va_w, tid, fVw);

  // ---- qp tile via MFMA; epilogue stores tq = tanh(proj) ----
  {
    const int h0 = wv * 16;
    const size_t qrow = (size_t)(b*TQN + qbase + (ln & 7))*HD;  // rows 8..15 dup
    f32x4 c = {0.f,0.f,0.f,0.f};
    #pragma unroll
    for (int ks = 0; ks < 4; ks++){
      short8 a = ld8bf(queries, qrow + ks*32 + quad*8, fQ);
      short8 w = ld8bf(Wa_w, (size_t)(h0 + ln)*HD + ks*32 + quad*8, fWw);
      c = __builtin_amdgcn_mfma_f32_16x16x32_bf16(a, w, c, 0,0,0);
    }
    const float wb = ld1(Wa_b, h0 + ln, fWb);
    #pragma unroll
    for (int r = 0; r < 4; r++){      // D: col=ln, row=quad*4+r
      const int row = quad*4 + r;
      if (row < QT) qp_s[row*QSTR + h0 + ln] = tanh_acc(c[r] + wb);
    }
  }

  // ---- hoist Ua B-frags for wave's n-tile ----
  short8 ub[4];
  float ubias;
  {
    const int h0 = wv * 16;
    #pragma unroll
    for (int ks = 0; ks < 4; ks++)
      ub[ks] = ld8bf(Ua_w, (size_t)(h0 + ln)*HD + ks*32 + quad*8, fUw);
    ubias = ld1(Ua_b, h0 + ln, fUb);
  }

  stage_keys(keys, fK, keys_s, b, 0, tid);
  __syncthreads();   // qp_s(tq), va_s, keys_s(0) complete

  const float4* q4p = (const float4*)(qp_s + wv*QSTR);   // wave-uniform tq row
  const float4* v4p = (const float4*)va_s;

  // ======== main loop: 8 key tiles ========
  for (int kt = 0; kt < 8; kt++){
    // kp MFMA: keys_tile @ Ua^T + b; epilogue stores tk = tanh(.)
    f32x4 kc[4];
    #pragma unroll
    for (int mt = 0; mt < 4; mt++) kc[mt] = (f32x4){0.f,0.f,0.f,0.f};
    #pragma unroll
    for (int ks = 0; ks < 4; ks++){
      short8 af[4];
      #pragma unroll
      for (int mt = 0; mt < 4; mt++)
        af[mt] = *(const short8*)(keys_s + (mt*16 + ln)*KBSTR + ks*32 + quad*8);
      #pragma unroll
      for (int mt = 0; mt < 4; mt++)
        kc[mt] = __builtin_amdgcn_mfma_f32_16x16x32_bf16(af[mt], ub[ks], kc[mt], 0,0,0);
    }
    __syncthreads();   // keys_s reads + prev phase-1 kp_s reads complete

    #pragma unroll
    for (int mt = 0; mt < 4; mt++)
      #pragma unroll
      for (int r = 0; r < 4; r++)
        kp_s[(mt*16 + quad*4 + r)*KSTR + wv*16 + ln] = tanh_acc(kc[mt][r] + ubias);
    if (kt < 7) stage_keys(keys, fK, keys_s, b, kt+1, tid);
    __syncthreads();

    // phase 1: thread = (q=wv, key=lane); trans-free inner loop
    float acc = 0.f;
    const float4* krow4 = (const float4*)(kp_s + lane*KSTR);
    #pragma unroll 8
    for (int hh = 0; hh < 32; hh++){
      const float4 tk = krow4[hh];
      const float4 tq = q4p[hh];
      const float4 vv = v4p[hh];
      float n0 = tq.x + tk.x, d0 = fmaf(tq.x, tk.x, 1.f);
      float n1 = tq.y + tk.y, d1 = fmaf(tq.y, tk.y, 1.f);
      float n2 = tq.z + tk.z, d2 = fmaf(tq.z, tk.z, 1.f);
      float n3 = tq.w + tk.w, d3 = fmaf(tq.w, tk.w, 1.f);
      acc = fmaf(vv.x, n0*fast_rcp(d0), acc);
      acc = fmaf(vv.y, n1*fast_rcp(d1), acc);
      acc = fmaf(vv.z, n2*fast_rcp(d2), acc);
      acc = fmaf(vv.w, n3*fast_rcp(d3), acc);
    }
    sc_s[wv*TKN + kt*KTILE + lane] = acc;
    // no barrier: next iter's MFMA touches only keys_s (barrier-protected)
  }
  __syncthreads();   // all scores visible

  // ======== softmax: wave wv owns query row wv ========
  {
    float vals[8];
    float m = -1e30f;
    #pragma unroll
    for (int j = 0; j < 8; j++){
      vals[j] = sc_s[wv*TKN + lane + 64*j];
      m = fmaxf(m, vals[j]);
    }
    #pragma unroll
    for (int o = 32; o > 0; o >>= 1) m = fmaxf(m, __shfl_xor(m, o));
    float sum = 0.f;
    #pragma unroll
    for (int j = 0; j < 8; j++){
      vals[j] = __builtin_amdgcn_exp2f((vals[j]-m)*1.4426950408889634f);
      sum += vals[j];
    }
    #pragma unroll
    for (int o = 32; o > 0; o >>= 1) sum += __shfl_xor(sum, o);
    const float inv = 1.f / sum;
    const size_t wbase = (size_t)NB*TQN*HD + (size_t)(b*TQN + qbase + wv)*TKN;
    #pragma unroll
    for (int j = 0; j < 8; j++){
      const float w = vals[j]*inv;
      sc_s[wv*TKN + lane + 64*j] = w;
      if (fQ) ((float*)out)[wbase + lane + 64*j] = w;
      else    ((unsigned short*)out)[wbase + lane + 64*j] = (unsigned short)f2bf(w);
    }
  }
  __syncthreads();

  // ======== phase 3: contexts = weights @ keys ========
  {
    const int h0 = ln * 8;
    float a[8];
    #pragma unroll
    for (int t = 0; t < 8; t++) a[t] = 0.f;
    for (int kt = 0; kt < 8; kt++){
      if (fK){
        const float4* src = (const float4*)((const float*)keys + (size_t)(b*TKN + kt*KTILE)*HD);
        #pragma unroll
        for (int j = 0; j < 4; j++){
          const int f = tid + 512*j;
          const int k = f >> 5;
          const int h = (f & 31) * 4;
          *(float4*)(kp_s + k*KSTR + h) = src[f];
        }
      } else {
        const uint4* src = (const uint4*)((const unsigned short*)keys + (size_t)(b*TKN + kt*KTILE)*HD);
        #pragma unroll
        for (int j = 0; j < 2; j++){
          const int f = tid + 512*j;
          const int k = f >> 4;
          const int h = (f & 15) * 8;
          uint4 v = src[f];
          float4 d0, d1;
          d0.x = lo16(v.x); d0.y = hi16(v.x); d0.z = lo16(v.y); d0.w = hi16(v.y);
          d1.x = lo16(v.z); d1.y = hi16(v.z); d1.z = lo16(v.w); d1.w = hi16(v.w);
          *(float4*)(kp_s + k*KSTR + h)     = d0;
          *(float4*)(kp_s + k*KSTR + h + 4) = d1;
        }
      }
      __syncthreads();
      const float* wr = sc_s + wv*TKN + kt*KTILE;
      #pragma unroll 4
      for (int i = 0; i < 16; i++){
        const int k = 4*i + quad;
        const float w = wr[k];
        const float4 k0 = *(const float4*)(kp_s + k*KSTR + h0);
        const float4 k1 = *(const float4*)(kp_s + k*KSTR + h0 + 4);
        a[0] = fmaf(w, k0.x, a[0]); a[1] = fmaf(w, k0.y, a[1]);
        a[2] = fmaf(w, k0.z, a[2]); a[3] = fmaf(w, k0.w, a[3]);
        a[4] = fmaf(w, k1.x, a[4]); a[5] = fmaf(w, k1.y, a[5]);
        a[6] = fmaf(w, k1.z, a[6]); a[7] = fmaf(w, k1.w, a[7]);
      }
      __syncthreads();
    }
    #pragma unroll
    for (int t = 0; t < 8; t++){
      a[t] += __shfl_xor(a[t], 16);
      a[t] += __shfl_xor(a[t], 32);
    }
    if (quad == 0){
      const size_t crow = (size_t)(b*TQN + qbase + wv)*HD + h0;
      if (fQ){
        float* oc = (float*)out;
        *(float4*)(oc + crow)     = (float4){a[0],a[1],a[2],a[3]};
        *(float4*)(oc + crow + 4) = (float4){a[4],a[5],a[6],a[7]};
      } else {
        uint4 o;
        o.x = f2bf(a[0]) | (f2bf(a[1]) << 16);
        o.y = f2bf(a[2]) | (f2bf(a[3]) << 16);
        o.z = f2bf(a[4]) | (f2bf(a[5]) << 16);
        o.w = f2bf(a[6]) | (f2bf(a[7]) << 16);
        *(uint4*)((unsigned short*)out + crow) = o;
      }
    }
  }
}

extern "C" void kernel_launch(void* const* d_in, const int* in_sizes, int n_in,
                              void* d_out, int out_size, void* d_ws, size_t ws_size,
                              hipStream_t stream) {
  (void)in_sizes; (void)n_in; (void)out_size; (void)d_ws; (void)ws_size;
  fused_kernel<<<512, 512, 0, stream>>>(d_in[0], d_in[1], d_in[2], d_in[3],
                                        d_in[4], d_in[5], d_in[6], d_out);
}

// Round 8
// 161.056 us; speedup vs baseline: 1.3525x; 1.0211x over previous
//
#include <hip/hip_runtime.h>
#include <hip/hip_bf16.h>
#include <stdint.h>

#define HD 128
#define NB 8
#define TQN 512
#define TKN 512
#define QT 8        // queries per block
#define KTILE 64
#define KSTR 132    // kp_s row stride (floats): b128-aligned, conflict-free
#define QSTR 132    // qp_s row stride (floats)
#define KBSTR 136   // keys_s row stride (bf16)

typedef __attribute__((ext_vector_type(8))) short short8;  // 8 bf16 (4 VGPRs)
typedef __attribute__((ext_vector_type(4))) float f32x4;   // MFMA C/D

static __device__ __forceinline__ float lo16(uint32_t w){
  union { uint32_t i; float f; } v; v.i = w << 16; return v.f;
}
static __device__ __forceinline__ float hi16(uint32_t w){
  union { uint32_t i; float f; } v; v.i = w & 0xffff0000u; return v.f;
}
static __device__ __forceinline__ float bf2f(unsigned short u){
  union { uint32_t i; float f; } v; v.i = ((uint32_t)u) << 16; return v.f;
}
static __device__ __forceinline__ uint32_t f2bf(float f){   // RNE
  union { float f; uint32_t i; } v; v.f = f;
  uint32_t u = v.i;
  u += 0x7fffu + ((u >> 16) & 1u);
  return u >> 16;
}

// accurate tanh via trans pipe: exp2 + hw rcp (~1 ulp each).
static __device__ __forceinline__ float tanh_acc(float x){
  float e = __builtin_amdgcn_exp2f(x * 2.8853900817779268f);  // 2^(2x*log2e)
  return fmaf(-2.0f, __builtin_amdgcn_rcpf(e + 1.0f), 1.0f);
}

// load 1 element as float; load 8 consecutive elements as bf16 fragment.
static __device__ __forceinline__ float ld1(const void* p, size_t idx, bool f32){
  return f32 ? ((const float*)p)[idx] : bf2f(((const unsigned short*)p)[idx]);
}
static __device__ __forceinline__ short8 ld8bf(const void* p, size_t idx, bool f32){
  short8 r;
  if (f32){
    const float* s = (const float*)p + idx;
    #pragma unroll
    for (int i = 0; i < 8; i++) r[i] = (short)f2bf(s[i]);
  } else {
    r = *(const short8*)((const unsigned short*)p + idx);
  }
  return r;
}

// stage 64x128 keys tile kt into LDS as bf16 (row stride KBSTR)
static __device__ __forceinline__ void stage_keys(const void* keys, bool fK,
    unsigned short* keys_s, int b, int kt, int tid){
  if (fK){
    const float4* src = (const float4*)((const float*)keys + (size_t)(b*TKN + kt*KTILE)*HD);
    #pragma unroll
    for (int j = 0; j < 4; j++){
      const int f = tid + 512*j;
      float4 v = src[f];
      const int k = f >> 5;
      const int h = (f & 31) * 4;
      uint2 p;
      p.x = f2bf(v.x) | (f2bf(v.y) << 16);
      p.y = f2bf(v.z) | (f2bf(v.w) << 16);
      *(uint2*)(keys_s + k*KBSTR + h) = p;
    }
  } else {
    const uint4* src = (const uint4*)((const unsigned short*)keys + (size_t)(b*TKN + kt*KTILE)*HD);
    #pragma unroll
    for (int j = 0; j < 2; j++){
      const int f = tid + 512*j;
      uint4 v = src[f];
      const int k = f >> 4;
      const int h = (f & 15) * 8;
      *(uint4*)(keys_s + k*KBSTR + h) = v;
    }
  }
}

// One block = (batch, 8-query tile); 512 blocks x 512 threads.
// Inner loop: tanh(q+k) = (tq+tk)/(1+tq*tk); minimal 4 VALU + 1 trans/elem.
__global__ __launch_bounds__(512, 4) void fused_kernel(
    const void* __restrict__ queries, const void* __restrict__ keys,
    const void* __restrict__ Wa_w,   const void* __restrict__ Wa_b,
    const void* __restrict__ Ua_w,   const void* __restrict__ Ua_b,
    const void* __restrict__ Va_w,
    void* __restrict__ out)
{
  __shared__ float qp_s[QT*QSTR];                       // tq: tanh(q-proj)
  __shared__ float va_s[HD];
  __shared__ __align__(16) unsigned short keys_s[KTILE*KBSTR]; // bf16 keys tile
  __shared__ __align__(16) float kp_s[KTILE*KSTR];      // tk (phase3: fp32 keys)
  __shared__ float sc_s[QT*TKN];                        // scores -> weights
  __shared__ unsigned int flg_s[8];

  const int tid = threadIdx.x;

  // ---- inlined dtype probe ----
  if (tid < 8) flg_s[tid] = 0;
  __syncthreads();
  {
    const void* ptrs[7] = {queries, keys, Wa_w, Wa_b, Ua_w, Ua_b, Va_w};
    const int grp = tid >> 5;
    const int l   = tid & 31;
    if (grp < 7){
      const unsigned short* p = (const unsigned short*)ptrs[grp];
      unsigned short a = p[2*l];
      unsigned short c = p[64 + 2*l];
      if (((a >> 7) & 0xFF) > 0x90 || ((c >> 7) & 0xFF) > 0x90)
        atomicOr(&flg_s[grp], 1u);
    }
  }
  __syncthreads();
  const bool fQ  = flg_s[0] != 0;   // also selects OUTPUT dtype
  const bool fK  = flg_s[1] != 0;
  const bool fWw = flg_s[2] != 0;
  const bool fWb = flg_s[3] != 0;
  const bool fUw = flg_s[4] != 0;
  const bool fUb = flg_s[5] != 0;
  const bool fVw = flg_s[6] != 0;
  // Va_b unused: constant score shift, softmax-invariant.

  const int lane = tid & 63;
  const int wv   = tid >> 6;        // wave 0..7
  const int ln   = lane & 15;
  const int quad = lane >> 4;
  const int b     = blockIdx.x >> 6;
  const int qbase = (blockIdx.x & 63) * QT;

  if (tid < HD) va_s[tid] = ld1(Va_w, tid, fVw);

  // ---- qp tile via MFMA; epilogue stores tq = tanh(proj) ----
  {
    const int h0 = wv * 16;
    const size_t qrow = (size_t)(b*TQN + qbase + (ln & 7))*HD;  // rows 8..15 dup
    f32x4 c = {0.f,0.f,0.f,0.f};
    #pragma unroll
    for (int ks = 0; ks < 4; ks++){
      short8 a = ld8bf(queries, qrow + ks*32 + quad*8, fQ);
      short8 w = ld8bf(Wa_w, (size_t)(h0 + ln)*HD + ks*32 + quad*8, fWw);
      c = __builtin_amdgcn_mfma_f32_16x16x32_bf16(a, w, c, 0,0,0);
    }
    const float wb = ld1(Wa_b, h0 + ln, fWb);
    #pragma unroll
    for (int r = 0; r < 4; r++){      // D: col=ln, row=quad*4+r
      const int row = quad*4 + r;
      if (row < QT) qp_s[row*QSTR + h0 + ln] = tanh_acc(c[r] + wb);
    }
  }

  // ---- hoist Ua B-frags for wave's n-tile ----
  short8 ub[4];
  float ubias;
  {
    const int h0 = wv * 16;
    #pragma unroll
    for (int ks = 0; ks < 4; ks++)
      ub[ks] = ld8bf(Ua_w, (size_t)(h0 + ln)*HD + ks*32 + quad*8, fUw);
    ubias = ld1(Ua_b, h0 + ln, fUb);
  }

  stage_keys(keys, fK, keys_s, b, 0, tid);
  __syncthreads();   // qp_s(tq), va_s, keys_s(0) complete

  const float4* q4p = (const float4*)(qp_s + wv*QSTR);   // wave-uniform tq row
  const float4* v4p = (const float4*)va_s;

  // ======== main loop: 8 key tiles ========
  for (int kt = 0; kt < 8; kt++){
    // kp MFMA: keys_tile @ Ua^T + b; epilogue stores tk = tanh(.)
    f32x4 kc[4];
    #pragma unroll
    for (int mt = 0; mt < 4; mt++) kc[mt] = (f32x4){0.f,0.f,0.f,0.f};
    #pragma unroll
    for (int ks = 0; ks < 4; ks++){
      short8 af[4];
      #pragma unroll
      for (int mt = 0; mt < 4; mt++)
        af[mt] = *(const short8*)(keys_s + (mt*16 + ln)*KBSTR + ks*32 + quad*8);
      #pragma unroll
      for (int mt = 0; mt < 4; mt++)
        kc[mt] = __builtin_amdgcn_mfma_f32_16x16x32_bf16(af[mt], ub[ks], kc[mt], 0,0,0);
    }
    __syncthreads();   // keys_s reads + prev phase-1 kp_s reads complete

    #pragma unroll
    for (int mt = 0; mt < 4; mt++)
      #pragma unroll
      for (int r = 0; r < 4; r++)
        kp_s[(mt*16 + quad*4 + r)*KSTR + wv*16 + ln] = tanh_acc(kc[mt][r] + ubias);
    if (kt < 7) stage_keys(keys, fK, keys_s, b, kt+1, tid);
    __syncthreads();

    // phase 1: thread = (q=wv, key=lane); 4 VALU + 1 trans per element,
    // 4 independent accumulators (no serial fma chain)
    float ac0 = 0.f, ac1 = 0.f, ac2 = 0.f, ac3 = 0.f;
    const float4* krow4 = (const float4*)(kp_s + lane*KSTR);
    #pragma unroll 8
    for (int hh = 0; hh < 32; hh++){
      const float4 tk = krow4[hh];
      const float4 tq = q4p[hh];
      const float4 vv = v4p[hh];
      float n0 = tq.x + tk.x, d0 = fmaf(tq.x, tk.x, 1.f);
      float n1 = tq.y + tk.y, d1 = fmaf(tq.y, tk.y, 1.f);
      float n2 = tq.z + tk.z, d2 = fmaf(tq.z, tk.z, 1.f);
      float n3 = tq.w + tk.w, d3 = fmaf(tq.w, tk.w, 1.f);
      ac0 = fmaf(vv.x * n0, __builtin_amdgcn_rcpf(d0), ac0);
      ac1 = fmaf(vv.y * n1, __builtin_amdgcn_rcpf(d1), ac1);
      ac2 = fmaf(vv.z * n2, __builtin_amdgcn_rcpf(d2), ac2);
      ac3 = fmaf(vv.w * n3, __builtin_amdgcn_rcpf(d3), ac3);
    }
    sc_s[wv*TKN + kt*KTILE + lane] = (ac0 + ac1) + (ac2 + ac3);
    // no barrier: next iter's MFMA touches only keys_s (barrier-protected)
  }
  __syncthreads();   // all scores visible

  // ======== softmax: wave wv owns query row wv ========
  {
    float vals[8];
    float m = -1e30f;
    #pragma unroll
    for (int j = 0; j < 8; j++){
      vals[j] = sc_s[wv*TKN + lane + 64*j];
      m = fmaxf(m, vals[j]);
    }
    #pragma unroll
    for (int o = 32; o > 0; o >>= 1) m = fmaxf(m, __shfl_xor(m, o));
    float sum = 0.f;
    #pragma unroll
    for (int j = 0; j < 8; j++){
      vals[j] = __builtin_amdgcn_exp2f((vals[j]-m)*1.4426950408889634f);
      sum += vals[j];
    }
    #pragma unroll
    for (int o = 32; o > 0; o >>= 1) sum += __shfl_xor(sum, o);
    const float inv = __builtin_amdgcn_rcpf(sum);
    const size_t wbase = (size_t)NB*TQN*HD + (size_t)(b*TQN + qbase + wv)*TKN;
    #pragma unroll
    for (int j = 0; j < 8; j++){
      const float w = vals[j]*inv;
      sc_s[wv*TKN + lane + 64*j] = w;
      if (fQ) ((float*)out)[wbase + lane + 64*j] = w;
      else    ((unsigned short*)out)[wbase + lane + 64*j] = (unsigned short)f2bf(w);
    }
  }
  __syncthreads();

  // ======== phase 3: contexts = weights @ keys ========
  {
    const int h0 = ln * 8;
    float a[8];
    #pragma unroll
    for (int t = 0; t < 8; t++) a[t] = 0.f;
    for (int kt = 0; kt < 8; kt++){
      if (fK){
        const float4* src = (const float4*)((const float*)keys + (size_t)(b*TKN + kt*KTILE)*HD);
        #pragma unroll
        for (int j = 0; j < 4; j++){
          const int f = tid + 512*j;
          const int k = f >> 5;
          const int h = (f & 31) * 4;
          *(float4*)(kp_s + k*KSTR + h) = src[f];
        }
      } else {
        const uint4* src = (const uint4*)((const unsigned short*)keys + (size_t)(b*TKN + kt*KTILE)*HD);
        #pragma unroll
        for (int j = 0; j < 2; j++){
          const int f = tid + 512*j;
          const int k = f >> 4;
          const int h = (f & 15) * 8;
          uint4 v = src[f];
          float4 d0, d1;
          d0.x = lo16(v.x); d0.y = hi16(v.x); d0.z = lo16(v.y); d0.w = hi16(v.y);
          d1.x = lo16(v.z); d1.y = hi16(v.z); d1.z = lo16(v.w); d1.w = hi16(v.w);
          *(float4*)(kp_s + k*KSTR + h)     = d0;
          *(float4*)(kp_s + k*KSTR + h + 4) = d1;
        }
      }
      __syncthreads();
      const float* wr = sc_s + wv*TKN + kt*KTILE;
      #pragma unroll 4
      for (int i = 0; i < 16; i++){
        const int k = 4*i + quad;
        const float w = wr[k];
        const float4 k0 = *(const float4*)(kp_s + k*KSTR + h0);
        const float4 k1 = *(const float4*)(kp_s + k*KSTR + h0 + 4);
        a[0] = fmaf(w, k0.x, a[0]); a[1] = fmaf(w, k0.y, a[1]);
        a[2] = fmaf(w, k0.z, a[2]); a[3] = fmaf(w, k0.w, a[3]);
        a[4] = fmaf(w, k1.x, a[4]); a[5] = fmaf(w, k1.y, a[5]);
        a[6] = fmaf(w, k1.z, a[6]); a[7] = fmaf(w, k1.w, a[7]);
      }
      __syncthreads();
    }
    #pragma unroll
    for (int t = 0; t < 8; t++){
      a[t] += __shfl_xor(a[t], 16);
      a[t] += __shfl_xor(a[t], 32);
    }
    if (quad == 0){
      const size_t crow = (size_t)(b*TQN + qbase + wv)*HD + h0;
      if (fQ){
        float* oc = (float*)out;
        *(float4*)(oc + crow)     = (float4){a[0],a[1],a[2],a[3]};
        *(float4*)(oc + crow + 4) = (float4){a[4],a[5],a[6],a[7]};
      } else {
        uint4 o;
        o.x = f2bf(a[0]) | (f2bf(a[1]) << 16);
        o.y = f2bf(a[2]) | (f2bf(a[3]) << 16);
        o.z = f2bf(a[4]) | (f2bf(a[5]) << 16);
        o.w = f2bf(a[6]) | (f2bf(a[7]) << 16);
        *(uint4*)((unsigned short*)out + crow) = o;
      }
    }
  }
}

extern "C" void kernel_launch(void* const* d_in, const int* in_sizes, int n_in,
                              void* d_out, int out_size, void* d_ws, size_t ws_size,
                              hipStream_t stream) {
  (void)in_sizes; (void)n_in; (void)out_size; (void)d_ws; (void)ws_size;
  fused_kernel<<<512, 512, 0, stream>>>(d_in[0], d_in[1], d_in[2], d_in[3],
                                        d_in[4], d_in[5], d_in[6], d_out);
}

// Round 9
// 158.365 us; speedup vs baseline: 1.3754x; 1.0170x over previous
//
#include <hip/hip_runtime.h>
#include <hip/hip_bf16.h>
#include <stdint.h>

#define HD 128
#define NB 8
#define TQN 512
#define TKN 512
#define QT 8        // queries per block
#define KTILE 64
#define KSTR 132    // kp_s row stride (floats): b128-aligned
#define QSTR 132    // qp_s row stride (floats)
#define KBSTR 136   // keys_s row stride (bf16)

typedef __attribute__((ext_vector_type(8))) short short8;  // 8 bf16 (4 VGPRs)
typedef __attribute__((ext_vector_type(4))) float f32x4;   // MFMA C/D

static __device__ __forceinline__ float lo16(uint32_t w){
  union { uint32_t i; float f; } v; v.i = w << 16; return v.f;
}
static __device__ __forceinline__ float hi16(uint32_t w){
  union { uint32_t i; float f; } v; v.i = w & 0xffff0000u; return v.f;
}
static __device__ __forceinline__ float bf2f(unsigned short u){
  union { uint32_t i; float f; } v; v.i = ((uint32_t)u) << 16; return v.f;
}
static __device__ __forceinline__ uint32_t f2bf(float f){   // RNE
  union { float f; uint32_t i; } v; v.f = f;
  uint32_t u = v.i;
  u += 0x7fffu + ((u >> 16) & 1u);
  return u >> 16;
}

// accurate tanh via trans pipe: exp2 + hw rcp (~1 ulp each).
static __device__ __forceinline__ float tanh_acc(float x){
  float e = __builtin_amdgcn_exp2f(x * 2.8853900817779268f);  // 2^(2x*log2e)
  return fmaf(-2.0f, __builtin_amdgcn_rcpf(e + 1.0f), 1.0f);
}

// cross-lane add via DPP (VALU pipe, no LDS): x += lane-permuted x
template<int CTRL>
static __device__ __forceinline__ float dpp_add(float x){
  union { float f; int i; } u; u.f = x;
  int y = __builtin_amdgcn_update_dpp(0, u.i, CTRL, 0xf, 0xf, true);
  union { int i; float f; } w; w.i = y;
  return x + w.f;
}

// load 1 element as float; load 8 consecutive elements as bf16 fragment.
static __device__ __forceinline__ float ld1(const void* p, size_t idx, bool f32){
  return f32 ? ((const float*)p)[idx] : bf2f(((const unsigned short*)p)[idx]);
}
static __device__ __forceinline__ short8 ld8bf(const void* p, size_t idx, bool f32){
  short8 r;
  if (f32){
    const float* s = (const float*)p + idx;
    #pragma unroll
    for (int i = 0; i < 8; i++) r[i] = (short)f2bf(s[i]);
  } else {
    r = *(const short8*)((const unsigned short*)p + idx);
  }
  return r;
}

// stage 64x128 keys tile kt into LDS as bf16 (row stride KBSTR)
static __device__ __forceinline__ void stage_keys(const void* keys, bool fK,
    unsigned short* keys_s, int b, int kt, int tid){
  if (fK){
    const float4* src = (const float4*)((const float*)keys + (size_t)(b*TKN + kt*KTILE)*HD);
    #pragma unroll
    for (int j = 0; j < 4; j++){
      const int f = tid + 512*j;
      float4 v = src[f];
      const int k = f >> 5;
      const int h = (f & 31) * 4;
      uint2 p;
      p.x = f2bf(v.x) | (f2bf(v.y) << 16);
      p.y = f2bf(v.z) | (f2bf(v.w) << 16);
      *(uint2*)(keys_s + k*KBSTR + h) = p;
    }
  } else {
    const uint4* src = (const uint4*)((const unsigned short*)keys + (size_t)(b*TKN + kt*KTILE)*HD);
    #pragma unroll
    for (int j = 0; j < 2; j++){
      const int f = tid + 512*j;
      uint4 v = src[f];
      const int k = f >> 4;
      const int h = (f & 15) * 8;
      *(uint4*)(keys_s + k*KBSTR + h) = v;
    }
  }
}

// One block = (batch, 8-query tile); 512 blocks x 512 threads.
// Phase-1: tq/va hoisted to VGPRs (kt-invariant), only tk read from LDS;
// octant partials reduced with DPP adds (VALU pipe). DS-instr minimized.
__global__ __launch_bounds__(512, 4) void fused_kernel(
    const void* __restrict__ queries, const void* __restrict__ keys,
    const void* __restrict__ Wa_w,   const void* __restrict__ Wa_b,
    const void* __restrict__ Ua_w,   const void* __restrict__ Ua_b,
    const void* __restrict__ Va_w,
    void* __restrict__ out)
{
  __shared__ float qp_s[QT*QSTR];                       // tq; later: ctx partials
  __shared__ float va_s[HD];
  __shared__ __align__(16) unsigned short keys_s[KTILE*KBSTR]; // bf16 keys tile
  __shared__ __align__(16) float kp_s[KTILE*KSTR];      // tk (phase3: fp32 keys)
  __shared__ float sc_s[QT*TKN];                        // scores -> weights
  __shared__ unsigned int flg_s[8];

  const int tid = threadIdx.x;

  // ---- inlined dtype probe ----
  if (tid < 8) flg_s[tid] = 0;
  __syncthreads();
  {
    const void* ptrs[7] = {queries, keys, Wa_w, Wa_b, Ua_w, Ua_b, Va_w};
    const int grp = tid >> 5;
    const int l   = tid & 31;
    if (grp < 7){
      const unsigned short* p = (const unsigned short*)ptrs[grp];
      unsigned short a = p[2*l];
      unsigned short c = p[64 + 2*l];
      if (((a >> 7) & 0xFF) > 0x90 || ((c >> 7) & 0xFF) > 0x90)
        atomicOr(&flg_s[grp], 1u);
    }
  }
  __syncthreads();
  const bool fQ  = flg_s[0] != 0;   // also selects OUTPUT dtype
  const bool fK  = flg_s[1] != 0;
  const bool fWw = flg_s[2] != 0;
  const bool fWb = flg_s[3] != 0;
  const bool fUw = flg_s[4] != 0;
  const bool fUb = flg_s[5] != 0;
  const bool fVw = flg_s[6] != 0;
  // Va_b unused: constant score shift, softmax-invariant.

  const int lane = tid & 63;
  const int wv   = tid >> 6;        // wave 0..7
  const int ln   = lane & 15;
  const int quad = lane >> 4;
  const int b     = blockIdx.x >> 6;
  const int qbase = (blockIdx.x & 63) * QT;

  if (tid < HD) va_s[tid] = ld1(Va_w, tid, fVw);

  // ---- qp tile via MFMA; epilogue stores tq = tanh(proj) ----
  {
    const int h0 = wv * 16;
    const size_t qrow = (size_t)(b*TQN + qbase + (ln & 7))*HD;  // rows 8..15 dup
    f32x4 c = {0.f,0.f,0.f,0.f};
    #pragma unroll
    for (int ks = 0; ks < 4; ks++){
      short8 a = ld8bf(queries, qrow + ks*32 + quad*8, fQ);
      short8 w = ld8bf(Wa_w, (size_t)(h0 + ln)*HD + ks*32 + quad*8, fWw);
      c = __builtin_amdgcn_mfma_f32_16x16x32_bf16(a, w, c, 0,0,0);
    }
    const float wb = ld1(Wa_b, h0 + ln, fWb);
    #pragma unroll
    for (int r = 0; r < 4; r++){      // D: col=ln, row=quad*4+r
      const int row = quad*4 + r;
      if (row < QT) qp_s[row*QSTR + h0 + ln] = tanh_acc(c[r] + wb);
    }
  }

  // ---- hoist Ua B-frags for wave's n-tile ----
  short8 ub[4];
  float ubias;
  {
    const int h0 = wv * 16;
    #pragma unroll
    for (int ks = 0; ks < 4; ks++)
      ub[ks] = ld8bf(Ua_w, (size_t)(h0 + ln)*HD + ks*32 + quad*8, fUw);
    ubias = ld1(Ua_b, h0 + ln, fUb);
  }

  stage_keys(keys, fK, keys_s, b, 0, tid);
  __syncthreads();   // qp_s(tq), va_s, keys_s(0) complete

  // ---- phase-1 hoist: lane = (key-slot s8, h-octant o8); 16-float h-slice ----
  const int s8 = lane >> 3;       // key-slot 0..7
  const int o8 = lane & 7;        // h-octant -> h in [o8*16, o8*16+16)
  float tqr[16], var[16], vat[16];
  {
    const float* qsrc = qp_s + wv*QSTR + o8*16;
    const float* vsrc = va_s + o8*16;
    #pragma unroll
    for (int c = 0; c < 4; c++){
      float4 t = *(const float4*)(qsrc + c*4);
      float4 v = *(const float4*)(vsrc + c*4);
      tqr[c*4+0]=t.x; tqr[c*4+1]=t.y; tqr[c*4+2]=t.z; tqr[c*4+3]=t.w;
      var[c*4+0]=v.x; var[c*4+1]=v.y; var[c*4+2]=v.z; var[c*4+3]=v.w;
      vat[c*4+0]=v.x*t.x; vat[c*4+1]=v.y*t.y; vat[c*4+2]=v.z*t.z; vat[c*4+3]=v.w*t.w;
    }
  }

  // ======== main loop: 8 key tiles ========
  for (int kt = 0; kt < 8; kt++){
    // kp MFMA: keys_tile @ Ua^T + b; epilogue stores tk = tanh(.)
    f32x4 kc[4];
    #pragma unroll
    for (int mt = 0; mt < 4; mt++) kc[mt] = (f32x4){0.f,0.f,0.f,0.f};
    #pragma unroll
    for (int ks = 0; ks < 4; ks++){
      short8 af[4];
      #pragma unroll
      for (int mt = 0; mt < 4; mt++)
        af[mt] = *(const short8*)(keys_s + (mt*16 + ln)*KBSTR + ks*32 + quad*8);
      #pragma unroll
      for (int mt = 0; mt < 4; mt++)
        kc[mt] = __builtin_amdgcn_mfma_f32_16x16x32_bf16(af[mt], ub[ks], kc[mt], 0,0,0);
    }
    __syncthreads();   // keys_s reads + prev phase-1 kp_s reads complete

    #pragma unroll
    for (int mt = 0; mt < 4; mt++)
      #pragma unroll
      for (int r = 0; r < 4; r++)
        kp_s[(mt*16 + quad*4 + r)*KSTR + wv*16 + ln] = tanh_acc(kc[mt][r] + ubias);
    if (kt < 7) stage_keys(keys, fK, keys_s, b, kt+1, tid);
    __syncthreads();

    // phase 1: lane handles 8 keys (i*8+s8) x 16 h; only tk from LDS.
    float acc[8];
    #pragma unroll
    for (int i = 0; i < 8; i++) acc[i] = 0.f;
    #pragma unroll
    for (int i = 0; i < 8; i++){
      const float* tk = kp_s + (i*8 + s8)*KSTR + o8*16;
      #pragma unroll
      for (int c = 0; c < 4; c++){
        const float4 kv = *(const float4*)(tk + c*4);
        acc[i] = fmaf(fmaf(var[c*4+0], kv.x, vat[c*4+0]),
                      __builtin_amdgcn_rcpf(fmaf(tqr[c*4+0], kv.x, 1.f)), acc[i]);
        acc[i] = fmaf(fmaf(var[c*4+1], kv.y, vat[c*4+1]),
                      __builtin_amdgcn_rcpf(fmaf(tqr[c*4+1], kv.y, 1.f)), acc[i]);
        acc[i] = fmaf(fmaf(var[c*4+2], kv.z, vat[c*4+2]),
                      __builtin_amdgcn_rcpf(fmaf(tqr[c*4+2], kv.z, 1.f)), acc[i]);
        acc[i] = fmaf(fmaf(var[c*4+3], kv.w, vat[c*4+3]),
                      __builtin_amdgcn_rcpf(fmaf(tqr[c*4+3], kv.w, 1.f)), acc[i]);
      }
    }
    // octant-group (8 lanes, same s8) reduction via DPP: xor1, xor2, mirror-8
    #pragma unroll
    for (int i = 0; i < 8; i++){
      float a = acc[i];
      a = dpp_add<0xB1>(a);    // quad_perm [1,0,3,2]  (xor 1)
      a = dpp_add<0x4E>(a);    // quad_perm [2,3,0,1]  (xor 2)
      a = dpp_add<0x141>(a);   // row_half_mirror      (xor 4 equivalent)
      acc[i] = a;
    }
    float sc = acc[0];
    #pragma unroll
    for (int i = 1; i < 8; i++) sc = (o8 == i) ? acc[i] : sc;
    sc_s[wv*TKN + kt*KTILE + o8*8 + s8] = sc;
    // no barrier: next iter's MFMA touches only keys_s (barrier-protected)
  }
  __syncthreads();   // all scores visible

  // ======== softmax: wave wv owns query row wv ========
  {
    float vals[8];
    float m = -1e30f;
    #pragma unroll
    for (int j = 0; j < 8; j++){
      vals[j] = sc_s[wv*TKN + lane + 64*j];
      m = fmaxf(m, vals[j]);
    }
    #pragma unroll
    for (int o = 32; o > 0; o >>= 1) m = fmaxf(m, __shfl_xor(m, o));
    float sum = 0.f;
    #pragma unroll
    for (int j = 0; j < 8; j++){
      vals[j] = __builtin_amdgcn_exp2f((vals[j]-m)*1.4426950408889634f);
      sum += vals[j];
    }
    #pragma unroll
    for (int o = 32; o > 0; o >>= 1) sum += __shfl_xor(sum, o);
    const float inv = __builtin_amdgcn_rcpf(sum);
    const size_t wbase = (size_t)NB*TQN*HD + (size_t)(b*TQN + qbase + wv)*TKN;
    #pragma unroll
    for (int j = 0; j < 8; j++){
      const float w = vals[j]*inv;
      sc_s[wv*TKN + lane + 64*j] = w;
      if (fQ) ((float*)out)[wbase + lane + 64*j] = w;
      else    ((unsigned short*)out)[wbase + lane + 64*j] = (unsigned short)f2bf(w);
    }
  }
  __syncthreads();

  // ======== phase 3: contexts = weights @ keys ========
  // wave: p2 = wv&3 -> queries {2p2, 2p2+1}; g2 = wv>>2 -> key half [g2*32,+32)
  {
    const int p2 = wv & 3;
    const int g2 = wv >> 2;
    const int h0 = ln * 8;
    float a0[8], a1[8];
    #pragma unroll
    for (int t = 0; t < 8; t++){ a0[t] = 0.f; a1[t] = 0.f; }
    for (int kt = 0; kt < 8; kt++){
      if (fK){
        const float4* src = (const float4*)((const float*)keys + (size_t)(b*TKN + kt*KTILE)*HD);
        #pragma unroll
        for (int j = 0; j < 4; j++){
          const int f = tid + 512*j;
          const int k = f >> 5;
          const int h = (f & 31) * 4;
          *(float4*)(kp_s + k*KSTR + h) = src[f];
        }
      } else {
        const uint4* src = (const uint4*)((const unsigned short*)keys + (size_t)(b*TKN + kt*KTILE)*HD);
        #pragma unroll
        for (int j = 0; j < 2; j++){
          const int f = tid + 512*j;
          const int k = f >> 4;
          const int h = (f & 15) * 8;
          uint4 v = src[f];
          float4 d0, d1;
          d0.x = lo16(v.x); d0.y = hi16(v.x); d0.z = lo16(v.y); d0.w = hi16(v.y);
          d1.x = lo16(v.z); d1.y = hi16(v.z); d1.z = lo16(v.w); d1.w = hi16(v.w);
          *(float4*)(kp_s + k*KSTR + h)     = d0;
          *(float4*)(kp_s + k*KSTR + h + 4) = d1;
        }
      }
      __syncthreads();
      const float* w0r = sc_s + (2*p2)*TKN + kt*KTILE + g2*32;
      const float* w1r = w0r + TKN;
      #pragma unroll
      for (int i = 0; i < 8; i++){
        const int k = i*4 + quad;
        const float w0 = w0r[k];
        const float w1 = w1r[k];
        const float* kr = kp_s + (g2*32 + k)*KSTR + h0;
        const float4 k0 = *(const float4*)(kr);
        const float4 k1 = *(const float4*)(kr + 4);
        a0[0]=fmaf(w0,k0.x,a0[0]); a0[1]=fmaf(w0,k0.y,a0[1]);
        a0[2]=fmaf(w0,k0.z,a0[2]); a0[3]=fmaf(w0,k0.w,a0[3]);
        a0[4]=fmaf(w0,k1.x,a0[4]); a0[5]=fmaf(w0,k1.y,a0[5]);
        a0[6]=fmaf(w0,k1.z,a0[6]); a0[7]=fmaf(w0,k1.w,a0[7]);
        a1[0]=fmaf(w1,k0.x,a1[0]); a1[1]=fmaf(w1,k0.y,a1[1]);
        a1[2]=fmaf(w1,k0.z,a1[2]); a1[3]=fmaf(w1,k0.w,a1[3]);
        a1[4]=fmaf(w1,k1.x,a1[4]); a1[5]=fmaf(w1,k1.y,a1[5]);
        a1[6]=fmaf(w1,k1.z,a1[6]); a1[7]=fmaf(w1,k1.w,a1[7]);
      }
      __syncthreads();
    }
    // cross-quad reduce (k split over quads within the wave)
    #pragma unroll
    for (int t = 0; t < 8; t++){
      a0[t] += __shfl_xor(a0[t], 16); a0[t] += __shfl_xor(a0[t], 32);
      a1[t] += __shfl_xor(a1[t], 16); a1[t] += __shfl_xor(a1[t], 32);
    }
    // combine the two key-halves (wave p2 vs p2+4) via qp_s (dead)
    float* part = qp_s;                 // 8 q x 128 h (flat, stride HD)
    if (g2 == 1 && quad == 0){
      *(float4*)(part + (2*p2  )*HD + h0    ) = (float4){a0[0],a0[1],a0[2],a0[3]};
      *(float4*)(part + (2*p2  )*HD + h0 + 4) = (float4){a0[4],a0[5],a0[6],a0[7]};
      *(float4*)(part + (2*p2+1)*HD + h0    ) = (float4){a1[0],a1[1],a1[2],a1[3]};
      *(float4*)(part + (2*p2+1)*HD + h0 + 4) = (float4){a1[4],a1[5],a1[6],a1[7]};
    }
    __syncthreads();
    if (g2 == 0 && quad == 0){
      const float4 p00 = *(const float4*)(part + (2*p2  )*HD + h0    );
      const float4 p01 = *(const float4*)(part + (2*p2  )*HD + h0 + 4);
      const float4 p10 = *(const float4*)(part + (2*p2+1)*HD + h0    );
      const float4 p11 = *(const float4*)(part + (2*p2+1)*HD + h0 + 4);
      const size_t crow0 = (size_t)(b*TQN + qbase + 2*p2    )*HD + h0;
      const size_t crow1 = (size_t)(b*TQN + qbase + 2*p2 + 1)*HD + h0;
      if (fQ){
        float* oc = (float*)out;
        *(float4*)(oc + crow0)     = (float4){a0[0]+p00.x, a0[1]+p00.y, a0[2]+p00.z, a0[3]+p00.w};
        *(float4*)(oc + crow0 + 4) = (float4){a0[4]+p01.x, a0[5]+p01.y, a0[6]+p01.z, a0[7]+p01.w};
        *(float4*)(oc + crow1)     = (float4){a1[0]+p10.x, a1[1]+p10.y, a1[2]+p10.z, a1[3]+p10.w};
        *(float4*)(oc + crow1 + 4) = (float4){a1[4]+p11.x, a1[5]+p11.y, a1[6]+p11.z, a1[7]+p11.w};
      } else {
        uint4 o0, o1;
        o0.x = f2bf(a0[0]+p00.x) | (f2bf(a0[1]+p00.y) << 16);
        o0.y = f2bf(a0[2]+p00.z) | (f2bf(a0[3]+p00.w) << 16);
        o0.z = f2bf(a0[4]+p01.x) | (f2bf(a0[5]+p01.y) << 16);
        o0.w = f2bf(a0[6]+p01.z) | (f2bf(a0[7]+p01.w) << 16);
        o1.x = f2bf(a1[0]+p10.x) | (f2bf(a1[1]+p10.y) << 16);
        o1.y = f2bf(a1[2]+p10.z) | (f2bf(a1[3]+p10.w) << 16);
        o1.z = f2bf(a1[4]+p11.x) | (f2bf(a1[5]+p11.y) << 16);
        o1.w = f2bf(a1[6]+p11.z) | (f2bf(a1[7]+p11.w) << 16);
        *(uint4*)((unsigned short*)out + crow0) = o0;
        *(uint4*)((unsigned short*)out + crow1) = o1;
      }
    }
  }
}

extern "C" void kernel_launch(void* const* d_in, const int* in_sizes, int n_in,
                              void* d_out, int out_size, void* d_ws, size_t ws_size,
                              hipStream_t stream) {
  (void)in_sizes; (void)n_in; (void)out_size; (void)d_ws; (void)ws_size;
  fused_kernel<<<512, 512, 0, stream>>>(d_in[0], d_in[1], d_in[2], d_in[3],
                                        d_in[4], d_in[5], d_in[6], d_out);
}

// Round 10
// 155.251 us; speedup vs baseline: 1.4030x; 1.0201x over previous
//
#include <hip/hip_runtime.h>
#include <hip/hip_bf16.h>
#include <stdint.h>

#define HD 128
#define NB 8
#define TQN 512
#define TKN 512
#define QT 8        // queries per block (K2 / fallback)
#define KTILE 64
#define KSTR 132    // padded row stride (floats): 2-way max bank aliasing
#define QSTR 132
#define KBSTR 136   // fallback keys_s row stride (bf16)

typedef __attribute__((ext_vector_type(8))) short short8;  // 8 bf16
typedef __attribute__((ext_vector_type(4))) float f32x4;   // MFMA C/D

static __device__ __forceinline__ float lo16(uint32_t w){
  union { uint32_t i; float f; } v; v.i = w << 16; return v.f;
}
static __device__ __forceinline__ float hi16(uint32_t w){
  union { uint32_t i; float f; } v; v.i = w & 0xffff0000u; return v.f;
}
static __device__ __forceinline__ float bf2f(unsigned short u){
  union { uint32_t i; float f; } v; v.i = ((uint32_t)u) << 16; return v.f;
}
static __device__ __forceinline__ uint32_t f2bf(float f){   // RNE
  union { float f; uint32_t i; } v; v.f = f;
  uint32_t u = v.i;
  u += 0x7fffu + ((u >> 16) & 1u);
  return u >> 16;
}
static __device__ __forceinline__ float tanh_acc(float x){
  float e = __builtin_amdgcn_exp2f(x * 2.8853900817779268f);
  return fmaf(-2.0f, __builtin_amdgcn_rcpf(e + 1.0f), 1.0f);
}
template<int CTRL>
static __device__ __forceinline__ float dpp_add(float x){
  union { float f; int i; } u; u.f = x;
  int y = __builtin_amdgcn_update_dpp(0, u.i, CTRL, 0xf, 0xf, true);
  union { int i; float f; } w; w.i = y;
  return x + w.f;
}
static __device__ __forceinline__ float ld1(const void* p, size_t idx, bool f32){
  return f32 ? ((const float*)p)[idx] : bf2f(((const unsigned short*)p)[idx]);
}
static __device__ __forceinline__ short8 ld8bf(const void* p, size_t idx, bool f32){
  short8 r;
  if (f32){
    const float* s = (const float*)p + idx;
    #pragma unroll
    for (int i = 0; i < 8; i++) r[i] = (short)f2bf(s[i]);
  } else {
    r = *(const short8*)((const unsigned short*)p + idx);
  }
  return r;
}

// ================= K1: tq/tk projection+tanh precompute =================
__global__ __launch_bounds__(256) void proj_kernel(
    const void* __restrict__ queries, const void* __restrict__ keys,
    const void* __restrict__ Wa_w,   const void* __restrict__ Wa_b,
    const void* __restrict__ Ua_w,   const void* __restrict__ Ua_b,
    float* __restrict__ tq_g, float* __restrict__ tk_g)
{
  __shared__ unsigned int flg_s[8];
  const int tid = threadIdx.x;
  if (tid < 8) flg_s[tid] = 0;
  __syncthreads();
  {
    const void* ptrs[6] = {queries, keys, Wa_w, Wa_b, Ua_w, Ua_b};
    const int grp = tid >> 5;
    const int l   = tid & 31;
    if (grp < 6){
      const unsigned short* p = (const unsigned short*)ptrs[grp];
      unsigned short a = p[2*l], c = p[64 + 2*l];
      if (((a >> 7) & 0xFF) > 0x90 || ((c >> 7) & 0xFF) > 0x90)
        atomicOr(&flg_s[grp], 1u);
    }
  }
  __syncthreads();
  const int lane = tid & 63, wv = tid >> 6, ln = lane & 15, quad = lane >> 4;
  const int row0 = blockIdx.x * 16;

  const void* x; const void* W; const void* bias; float* dst; int r;
  bool fx, fw, fb;
  if (row0 < NB*TQN){
    x = queries; W = Wa_w; bias = Wa_b; dst = tq_g; r = row0;
    fx = flg_s[0] != 0; fw = flg_s[2] != 0; fb = flg_s[3] != 0;
  } else {
    x = keys; W = Ua_w; bias = Ua_b; dst = tk_g; r = row0 - NB*TQN;
    fx = flg_s[1] != 0; fw = flg_s[4] != 0; fb = flg_s[5] != 0;
  }

  short8 a[4];
  #pragma unroll
  for (int ks = 0; ks < 4; ks++)
    a[ks] = ld8bf(x, (size_t)(r + ln)*HD + ks*32 + quad*8, fx);

  #pragma unroll
  for (int nt = 0; nt < 2; nt++){
    const int h0 = (2*wv + nt)*16;
    f32x4 c = {0.f,0.f,0.f,0.f};
    #pragma unroll
    for (int ks = 0; ks < 4; ks++)
      c = __builtin_amdgcn_mfma_f32_16x16x32_bf16(
            a[ks], ld8bf(W, (size_t)(h0 + ln)*HD + ks*32 + quad*8, fw), c, 0,0,0);
    const float wb = ld1(bias, h0 + ln, fb);
    #pragma unroll
    for (int r4 = 0; r4 < 4; r4++)   // D: col=ln, row=quad*4+r4
      dst[(size_t)(r + quad*4 + r4)*HD + h0 + ln] = tanh_acc(c[r4] + wb);
  }
}

// ================= K2: scores + softmax + contexts =================
__global__ __launch_bounds__(512, 6) void attn_kernel(
    const void* __restrict__ queries, const void* __restrict__ keys,
    const void* __restrict__ Va_w,
    const float* __restrict__ tq_g, const float* __restrict__ tk_g,
    void* __restrict__ out)
{
  __shared__ __align__(16) float tk_s[KTILE*KSTR];   // 33.8 KB (phase3: fp32 keys)
  __shared__ float sc_s[QT*TKN];                     // 16 KB (weights only)
  __shared__ unsigned int flg_s[4];

  const int tid = threadIdx.x;
  if (tid < 4) flg_s[tid] = 0;
  __syncthreads();
  {
    const void* ptrs[3] = {queries, keys, Va_w};
    const int grp = tid >> 5;
    const int l   = tid & 31;
    if (grp < 3){
      const unsigned short* p = (const unsigned short*)ptrs[grp];
      unsigned short a = p[2*l], c = p[64 + 2*l];
      if (((a >> 7) & 0xFF) > 0x90 || ((c >> 7) & 0xFF) > 0x90)
        atomicOr(&flg_s[grp], 1u);
    }
  }
  __syncthreads();
  const bool fQ  = flg_s[0] != 0;   // selects OUTPUT dtype
  const bool fK  = flg_s[1] != 0;
  const bool fVw = flg_s[2] != 0;

  const int lane = tid & 63;
  const int wv   = tid >> 6;        // wave 0..7 = query row
  const int ln   = lane & 15;
  const int quad = lane >> 4;
  const int s8   = lane >> 3;       // key-slot 0..7
  const int o8   = lane & 7;        // h-octant
  const int b     = blockIdx.x >> 6;
  const int qbase = (blockIdx.x & 63) * QT;

  // per-lane hoists: va slice + tq slice (16 floats each)
  float var[16], tqr[16];
  {
    #pragma unroll
    for (int j = 0; j < 16; j++) var[j] = ld1(Va_w, o8*16 + j, fVw);
    const float4* qsrc = (const float4*)(tq_g + (size_t)(b*TQN + qbase + wv)*HD + o8*16);
    #pragma unroll
    for (int c = 0; c < 4; c++){
      float4 t = qsrc[c];
      tqr[c*4+0]=t.x; tqr[c*4+1]=t.y; tqr[c*4+2]=t.z; tqr[c*4+3]=t.w;
    }
  }

  // ======== phase 1: 8 key tiles; scores accumulate in registers ========
  float sc8[8];
  for (int kt = 0; kt < 8; kt++){
    { // stage tk tile (fp32, padded)
      const float4* src = (const float4*)(tk_g + (size_t)(b*TKN + kt*KTILE)*HD);
      #pragma unroll
      for (int j = 0; j < 4; j++){
        const int f = tid + 512*j;
        const int k = f >> 5;
        const int h = (f & 31) * 4;
        *(float4*)(tk_s + k*KSTR + h) = src[f];
      }
    }
    __syncthreads();

    float acc[8];
    #pragma unroll
    for (int i = 0; i < 8; i++) acc[i] = 0.f;
    #pragma unroll
    for (int i = 0; i < 8; i++){
      const float* tk = tk_s + (i*8 + s8)*KSTR + o8*16;
      #pragma unroll
      for (int c = 0; c < 4; c++){
        const float4 kv = *(const float4*)(tk + c*4);
        acc[i] = fmaf(var[c*4+0]*(tqr[c*4+0]+kv.x),
                      __builtin_amdgcn_rcpf(fmaf(tqr[c*4+0], kv.x, 1.f)), acc[i]);
        acc[i] = fmaf(var[c*4+1]*(tqr[c*4+1]+kv.y),
                      __builtin_amdgcn_rcpf(fmaf(tqr[c*4+1], kv.y, 1.f)), acc[i]);
        acc[i] = fmaf(var[c*4+2]*(tqr[c*4+2]+kv.z),
                      __builtin_amdgcn_rcpf(fmaf(tqr[c*4+2], kv.z, 1.f)), acc[i]);
        acc[i] = fmaf(var[c*4+3]*(tqr[c*4+3]+kv.w),
                      __builtin_amdgcn_rcpf(fmaf(tqr[c*4+3], kv.w, 1.f)), acc[i]);
      }
    }
    #pragma unroll
    for (int i = 0; i < 8; i++){   // reduce over o8 group (lanes ^1,^2,^4)
      float a = acc[i];
      a = dpp_add<0xB1>(a);        // quad_perm xor1
      a = dpp_add<0x4E>(a);        // quad_perm xor2
      a = dpp_add<0x141>(a);       // row_half_mirror (xor4)
      acc[i] = a;
    }
    float sc = acc[0];
    #pragma unroll
    for (int i = 1; i < 8; i++) sc = (o8 == i) ? acc[i] : sc;
    sc8[kt] = sc;                  // score for key kt*64 + o8*8 + s8
    __syncthreads();
  }

  // ======== softmax fully in-wave (wave = one query row) ========
  {
    float m = sc8[0];
    #pragma unroll
    for (int j = 1; j < 8; j++) m = fmaxf(m, sc8[j]);
    #pragma unroll
    for (int o = 32; o > 0; o >>= 1) m = fmaxf(m, __shfl_xor(m, o));
    float sum = 0.f;
    #pragma unroll
    for (int j = 0; j < 8; j++){
      sc8[j] = __builtin_amdgcn_exp2f((sc8[j]-m)*1.4426950408889634f);
      sum += sc8[j];
    }
    #pragma unroll
    for (int o = 32; o > 0; o >>= 1) sum += __shfl_xor(sum, o);
    const float inv = __builtin_amdgcn_rcpf(sum);
    const size_t wbase = (size_t)NB*TQN*HD + (size_t)(b*TQN + qbase + wv)*TKN;
    #pragma unroll
    for (int j = 0; j < 8; j++){
      const float w = sc8[j]*inv;
      const int kk = j*KTILE + o8*8 + s8;
      sc_s[wv*TKN + kk] = w;
      if (fQ) ((float*)out)[wbase + kk] = w;
      else    ((unsigned short*)out)[wbase + kk] = (unsigned short)f2bf(w);
    }
  }
  __syncthreads();

  // ======== phase 3: contexts = weights @ keys ========
  // p2 = wv&3 -> queries {2p2,2p2+1}; g2 = wv>>2 -> key half [g2*32,+32)
  {
    const int p2 = wv & 3;
    const int g2 = wv >> 2;
    const int h0 = ln * 8;
    float a0[8], a1[8];
    #pragma unroll
    for (int t = 0; t < 8; t++){ a0[t] = 0.f; a1[t] = 0.f; }
    for (int kt = 0; kt < 8; kt++){
      if (fK){
        const float4* src = (const float4*)((const float*)keys + (size_t)(b*TKN + kt*KTILE)*HD);
        #pragma unroll
        for (int j = 0; j < 4; j++){
          const int f = tid + 512*j;
          const int k = f >> 5;
          const int h = (f & 31) * 4;
          *(float4*)(tk_s + k*KSTR + h) = src[f];
        }
      } else {
        const uint4* src = (const uint4*)((const unsigned short*)keys + (size_t)(b*TKN + kt*KTILE)*HD);
        #pragma unroll
        for (int j = 0; j < 2; j++){
          const int f = tid + 512*j;
          const int k = f >> 4;
          const int h = (f & 15) * 8;
          uint4 v = src[f];
          float4 d0, d1;
          d0.x = lo16(v.x); d0.y = hi16(v.x); d0.z = lo16(v.y); d0.w = hi16(v.y);
          d1.x = lo16(v.z); d1.y = hi16(v.z); d1.z = lo16(v.w); d1.w = hi16(v.w);
          *(float4*)(tk_s + k*KSTR + h)     = d0;
          *(float4*)(tk_s + k*KSTR + h + 4) = d1;
        }
      }
      __syncthreads();
      const float* w0r = sc_s + (2*p2)*TKN + kt*KTILE + g2*32;
      const float* w1r = w0r + TKN;
      #pragma unroll
      for (int i = 0; i < 8; i++){
        const int k = i*4 + quad;
        const float w0 = w0r[k];
        const float w1 = w1r[k];
        const float* kr = tk_s + (g2*32 + k)*KSTR + h0;
        const float4 k0 = *(const float4*)(kr);
        const float4 k1 = *(const float4*)(kr + 4);
        a0[0]=fmaf(w0,k0.x,a0[0]); a0[1]=fmaf(w0,k0.y,a0[1]);
        a0[2]=fmaf(w0,k0.z,a0[2]); a0[3]=fmaf(w0,k0.w,a0[3]);
        a0[4]=fmaf(w0,k1.x,a0[4]); a0[5]=fmaf(w0,k1.y,a0[5]);
        a0[6]=fmaf(w0,k1.z,a0[6]); a0[7]=fmaf(w0,k1.w,a0[7]);
        a1[0]=fmaf(w1,k0.x,a1[0]); a1[1]=fmaf(w1,k0.y,a1[1]);
        a1[2]=fmaf(w1,k0.z,a1[2]); a1[3]=fmaf(w1,k0.w,a1[3]);
        a1[4]=fmaf(w1,k1.x,a1[4]); a1[5]=fmaf(w1,k1.y,a1[5]);
        a1[6]=fmaf(w1,k1.z,a1[6]); a1[7]=fmaf(w1,k1.w,a1[7]);
      }
      __syncthreads();
    }
    #pragma unroll
    for (int t = 0; t < 8; t++){
      a0[t] += __shfl_xor(a0[t], 16); a0[t] += __shfl_xor(a0[t], 32);
      a1[t] += __shfl_xor(a1[t], 16); a1[t] += __shfl_xor(a1[t], 32);
    }
    float* part = sc_s;               // dead after loop's final barrier
    if (g2 == 1 && quad == 0){
      *(float4*)(part + (2*p2  )*HD + h0    ) = (float4){a0[0],a0[1],a0[2],a0[3]};
      *(float4*)(part + (2*p2  )*HD + h0 + 4) = (float4){a0[4],a0[5],a0[6],a0[7]};
      *(float4*)(part + (2*p2+1)*HD + h0    ) = (float4){a1[0],a1[1],a1[2],a1[3]};
      *(float4*)(part + (2*p2+1)*HD + h0 + 4) = (float4){a1[4],a1[5],a1[6],a1[7]};
    }
    __syncthreads();
    if (g2 == 0 && quad == 0){
      const float4 p00 = *(const float4*)(part + (2*p2  )*HD + h0    );
      const float4 p01 = *(const float4*)(part + (2*p2  )*HD + h0 + 4);
      const float4 p10 = *(const float4*)(part + (2*p2+1)*HD + h0    );
      const float4 p11 = *(const float4*)(part + (2*p2+1)*HD + h0 + 4);
      const size_t crow0 = (size_t)(b*TQN + qbase + 2*p2    )*HD + h0;
      const size_t crow1 = (size_t)(b*TQN + qbase + 2*p2 + 1)*HD + h0;
      if (fQ){
        float* oc = (float*)out;
        *(float4*)(oc + crow0)     = (float4){a0[0]+p00.x, a0[1]+p00.y, a0[2]+p00.z, a0[3]+p00.w};
        *(float4*)(oc + crow0 + 4) = (float4){a0[4]+p01.x, a0[5]+p01.y, a0[6]+p01.z, a0[7]+p01.w};
        *(float4*)(oc + crow1)     = (float4){a1[0]+p10.x, a1[1]+p10.y, a1[2]+p10.z, a1[3]+p10.w};
        *(float4*)(oc + crow1 + 4) = (float4){a1[4]+p11.x, a1[5]+p11.y, a1[6]+p11.z, a1[7]+p11.w};
      } else {
        uint4 o0, o1;
        o0.x = f2bf(a0[0]+p00.x) | (f2bf(a0[1]+p00.y) << 16);
        o0.y = f2bf(a0[2]+p00.z) | (f2bf(a0[3]+p00.w) << 16);
        o0.z = f2bf(a0[4]+p01.x) | (f2bf(a0[5]+p01.y) << 16);
        o0.w = f2bf(a0[6]+p01.z) | (f2bf(a0[7]+p01.w) << 16);
        o1.x = f2bf(a1[0]+p10.x) | (f2bf(a1[1]+p10.y) << 16);
        o1.y = f2bf(a1[2]+p10.z) | (f2bf(a1[3]+p10.w) << 16);
        o1.z = f2bf(a1[4]+p11.x) | (f2bf(a1[5]+p11.y) << 16);
        o1.w = f2bf(a1[6]+p11.z) | (f2bf(a1[7]+p11.w) << 16);
        *(uint4*)((unsigned short*)out + crow0) = o0;
        *(uint4*)((unsigned short*)out + crow1) = o1;
      }
    }
  }
}

// ================= fallback: R9 single kernel (passes @ ~101 us) =========
__global__ __launch_bounds__(512, 4) void fused_kernel(
    const void* __restrict__ queries, const void* __restrict__ keys,
    const void* __restrict__ Wa_w,   const void* __restrict__ Wa_b,
    const void* __restrict__ Ua_w,   const void* __restrict__ Ua_b,
    const void* __restrict__ Va_w,
    void* __restrict__ out)
{
  __shared__ float qp_s[QT*QSTR];
  __shared__ float va_s[HD];
  __shared__ __align__(16) unsigned short keys_s[KTILE*KBSTR];
  __shared__ __align__(16) float kp_s[KTILE*KSTR];
  __shared__ float sc_s[QT*TKN];
  __shared__ unsigned int flg_s[8];

  const int tid = threadIdx.x;
  if (tid < 8) flg_s[tid] = 0;
  __syncthreads();
  {
    const void* ptrs[7] = {queries, keys, Wa_w, Wa_b, Ua_w, Ua_b, Va_w};
    const int grp = tid >> 5;
    const int l   = tid & 31;
    if (grp < 7){
      const unsigned short* p = (const unsigned short*)ptrs[grp];
      unsigned short a = p[2*l], c = p[64 + 2*l];
      if (((a >> 7) & 0xFF) > 0x90 || ((c >> 7) & 0xFF) > 0x90)
        atomicOr(&flg_s[grp], 1u);
    }
  }
  __syncthreads();
  const bool fQ  = flg_s[0] != 0;
  const bool fK  = flg_s[1] != 0;
  const bool fWw = flg_s[2] != 0;
  const bool fWb = flg_s[3] != 0;
  const bool fUw = flg_s[4] != 0;
  const bool fUb = flg_s[5] != 0;
  const bool fVw = flg_s[6] != 0;

  const int lane = tid & 63;
  const int wv   = tid >> 6;
  const int ln   = lane & 15;
  const int quad = lane >> 4;
  const int b     = blockIdx.x >> 6;
  const int qbase = (blockIdx.x & 63) * QT;

  if (tid < HD) va_s[tid] = ld1(Va_w, tid, fVw);
  {
    const int h0 = wv * 16;
    const size_t qrow = (size_t)(b*TQN + qbase + (ln & 7))*HD;
    f32x4 c = {0.f,0.f,0.f,0.f};
    #pragma unroll
    for (int ks = 0; ks < 4; ks++){
      short8 a = ld8bf(queries, qrow + ks*32 + quad*8, fQ);
      short8 w = ld8bf(Wa_w, (size_t)(h0 + ln)*HD + ks*32 + quad*8, fWw);
      c = __builtin_amdgcn_mfma_f32_16x16x32_bf16(a, w, c, 0,0,0);
    }
    const float wb = ld1(Wa_b, h0 + ln, fWb);
    #pragma unroll
    for (int r = 0; r < 4; r++){
      const int row = quad*4 + r;
      if (row < QT) qp_s[row*QSTR + h0 + ln] = tanh_acc(c[r] + wb);
    }
  }
  short8 ub[4];
  float ubias;
  {
    const int h0 = wv * 16;
    #pragma unroll
    for (int ks = 0; ks < 4; ks++)
      ub[ks] = ld8bf(Ua_w, (size_t)(h0 + ln)*HD + ks*32 + quad*8, fUw);
    ubias = ld1(Ua_b, h0 + ln, fUb);
  }
  { // stage keys tile 0
    if (fK){
      const float4* src = (const float4*)((const float*)keys + (size_t)(b*TKN)*HD);
      #pragma unroll
      for (int j = 0; j < 4; j++){
        const int f = tid + 512*j;
        float4 v = src[f];
        const int k = f >> 5, h = (f & 31)*4;
        uint2 p;
        p.x = f2bf(v.x) | (f2bf(v.y) << 16);
        p.y = f2bf(v.z) | (f2bf(v.w) << 16);
        *(uint2*)(keys_s + k*KBSTR + h) = p;
      }
    } else {
      const uint4* src = (const uint4*)((const unsigned short*)keys + (size_t)(b*TKN)*HD);
      #pragma unroll
      for (int j = 0; j < 2; j++){
        const int f = tid + 512*j;
        uint4 v = src[f];
        const int k = f >> 4, h = (f & 15)*8;
        *(uint4*)(keys_s + k*KBSTR + h) = v;
      }
    }
  }
  __syncthreads();

  const int s8 = lane >> 3;
  const int o8 = lane & 7;
  float tqr[16], var[16], vat[16];
  {
    const float* qsrc = qp_s + wv*QSTR + o8*16;
    const float* vsrc = va_s + o8*16;
    #pragma unroll
    for (int c = 0; c < 4; c++){
      float4 t = *(const float4*)(qsrc + c*4);
      float4 v = *(const float4*)(vsrc + c*4);
      tqr[c*4+0]=t.x; tqr[c*4+1]=t.y; tqr[c*4+2]=t.z; tqr[c*4+3]=t.w;
      var[c*4+0]=v.x; var[c*4+1]=v.y; var[c*4+2]=v.z; var[c*4+3]=v.w;
      vat[c*4+0]=v.x*t.x; vat[c*4+1]=v.y*t.y; vat[c*4+2]=v.z*t.z; vat[c*4+3]=v.w*t.w;
    }
  }
  for (int kt = 0; kt < 8; kt++){
    f32x4 kc[4];
    #pragma unroll
    for (int mt = 0; mt < 4; mt++) kc[mt] = (f32x4){0.f,0.f,0.f,0.f};
    #pragma unroll
    for (int ks = 0; ks < 4; ks++){
      short8 af[4];
      #pragma unroll
      for (int mt = 0; mt < 4; mt++)
        af[mt] = *(const short8*)(keys_s + (mt*16 + ln)*KBSTR + ks*32 + quad*8);
      #pragma unroll
      for (int mt = 0; mt < 4; mt++)
        kc[mt] = __builtin_amdgcn_mfma_f32_16x16x32_bf16(af[mt], ub[ks], kc[mt], 0,0,0);
    }
    __syncthreads();
    #pragma unroll
    for (int mt = 0; mt < 4; mt++)
      #pragma unroll
      for (int r = 0; r < 4; r++)
        kp_s[(mt*16 + quad*4 + r)*KSTR + wv*16 + ln] = tanh_acc(kc[mt][r] + ubias);
    if (kt < 7){
      if (fK){
        const float4* src = (const float4*)((const float*)keys + (size_t)(b*TKN + (kt+1)*KTILE)*HD);
        #pragma unroll
        for (int j = 0; j < 4; j++){
          const int f = tid + 512*j;
          float4 v = src[f];
          const int k = f >> 5, h = (f & 31)*4;
          uint2 p;
          p.x = f2bf(v.x) | (f2bf(v.y) << 16);
          p.y = f2bf(v.z) | (f2bf(v.w) << 16);
          *(uint2*)(keys_s + k*KBSTR + h) = p;
        }
      } else {
        const uint4* src = (const uint4*)((const unsigned short*)keys + (size_t)(b*TKN + (kt+1)*KTILE)*HD);
        #pragma unroll
        for (int j = 0; j < 2; j++){
          const int f = tid + 512*j;
          uint4 v = src[f];
          const int k = f >> 4, h = (f & 15)*8;
          *(uint4*)(keys_s + k*KBSTR + h) = v;
        }
      }
    }
    __syncthreads();
    float acc[8];
    #pragma unroll
    for (int i = 0; i < 8; i++) acc[i] = 0.f;
    #pragma unroll
    for (int i = 0; i < 8; i++){
      const float* tk = kp_s + (i*8 + s8)*KSTR + o8*16;
      #pragma unroll
      for (int c = 0; c < 4; c++){
        const float4 kv = *(const float4*)(tk + c*4);
        acc[i] = fmaf(fmaf(var[c*4+0], kv.x, vat[c*4+0]),
                      __builtin_amdgcn_rcpf(fmaf(tqr[c*4+0], kv.x, 1.f)), acc[i]);
        acc[i] = fmaf(fmaf(var[c*4+1], kv.y, vat[c*4+1]),
                      __builtin_amdgcn_rcpf(fmaf(tqr[c*4+1], kv.y, 1.f)), acc[i]);
        acc[i] = fmaf(fmaf(var[c*4+2], kv.z, vat[c*4+2]),
                      __builtin_amdgcn_rcpf(fmaf(tqr[c*4+2], kv.z, 1.f)), acc[i]);
        acc[i] = fmaf(fmaf(var[c*4+3], kv.w, vat[c*4+3]),
                      __builtin_amdgcn_rcpf(fmaf(tqr[c*4+3], kv.w, 1.f)), acc[i]);
      }
    }
    #pragma unroll
    for (int i = 0; i < 8; i++){
      float a = acc[i];
      a = dpp_add<0xB1>(a);
      a = dpp_add<0x4E>(a);
      a = dpp_add<0x141>(a);
      acc[i] = a;
    }
    float sc = acc[0];
    #pragma unroll
    for (int i = 1; i < 8; i++) sc = (o8 == i) ? acc[i] : sc;
    sc_s[wv*TKN + kt*KTILE + o8*8 + s8] = sc;
  }
  __syncthreads();
  {
    float vals[8];
    float m = -1e30f;
    #pragma unroll
    for (int j = 0; j < 8; j++){
      vals[j] = sc_s[wv*TKN + lane + 64*j];
      m = fmaxf(m, vals[j]);
    }
    #pragma unroll
    for (int o = 32; o > 0; o >>= 1) m = fmaxf(m, __shfl_xor(m, o));
    float sum = 0.f;
    #pragma unroll
    for (int j = 0; j < 8; j++){
      vals[j] = __builtin_amdgcn_exp2f((vals[j]-m)*1.4426950408889634f);
      sum += vals[j];
    }
    #pragma unroll
    for (int o = 32; o > 0; o >>= 1) sum += __shfl_xor(sum, o);
    const float inv = __builtin_amdgcn_rcpf(sum);
    const size_t wbase = (size_t)NB*TQN*HD + (size_t)(b*TQN + qbase + wv)*TKN;
    #pragma unroll
    for (int j = 0; j < 8; j++){
      const float w = vals[j]*inv;
      sc_s[wv*TKN + lane + 64*j] = w;
      if (fQ) ((float*)out)[wbase + lane + 64*j] = w;
      else    ((unsigned short*)out)[wbase + lane + 64*j] = (unsigned short)f2bf(w);
    }
  }
  __syncthreads();
  {
    const int p2 = wv & 3;
    const int g2 = wv >> 2;
    const int h0 = ln * 8;
    float a0[8], a1[8];
    #pragma unroll
    for (int t = 0; t < 8; t++){ a0[t] = 0.f; a1[t] = 0.f; }
    for (int kt = 0; kt < 8; kt++){
      if (fK){
        const float4* src = (const float4*)((const float*)keys + (size_t)(b*TKN + kt*KTILE)*HD);
        #pragma unroll
        for (int j = 0; j < 4; j++){
          const int f = tid + 512*j;
          const int k = f >> 5, h = (f & 31)*4;
          *(float4*)(kp_s + k*KSTR + h) = src[f];
        }
      } else {
        const uint4* src = (const uint4*)((const unsigned short*)keys + (size_t)(b*TKN + kt*KTILE)*HD);
        #pragma unroll
        for (int j = 0; j < 2; j++){
          const int f = tid + 512*j;
          const int k = f >> 4, h = (f & 15)*8;
          uint4 v = src[f];
          float4 d0, d1;
          d0.x = lo16(v.x); d0.y = hi16(v.x); d0.z = lo16(v.y); d0.w = hi16(v.y);
          d1.x = lo16(v.z); d1.y = hi16(v.z); d1.z = lo16(v.w); d1.w = hi16(v.w);
          *(float4*)(kp_s + k*KSTR + h)     = d0;
          *(float4*)(kp_s + k*KSTR + h + 4) = d1;
        }
      }
      __syncthreads();
      const float* w0r = sc_s + (2*p2)*TKN + kt*KTILE + g2*32;
      const float* w1r = w0r + TKN;
      #pragma unroll
      for (int i = 0; i < 8; i++){
        const int k = i*4 + quad;
        const float w0 = w0r[k];
        const float w1 = w1r[k];
        const float* kr = kp_s + (g2*32 + k)*KSTR + h0;
        const float4 k0 = *(const float4*)(kr);
        const float4 k1 = *(const float4*)(kr + 4);
        a0[0]=fmaf(w0,k0.x,a0[0]); a0[1]=fmaf(w0,k0.y,a0[1]);
        a0[2]=fmaf(w0,k0.z,a0[2]); a0[3]=fmaf(w0,k0.w,a0[3]);
        a0[4]=fmaf(w0,k1.x,a0[4]); a0[5]=fmaf(w0,k1.y,a0[5]);
        a0[6]=fmaf(w0,k1.z,a0[6]); a0[7]=fmaf(w0,k1.w,a0[7]);
        a1[0]=fmaf(w1,k0.x,a1[0]); a1[1]=fmaf(w1,k0.y,a1[1]);
        a1[2]=fmaf(w1,k0.z,a1[2]); a1[3]=fmaf(w1,k0.w,a1[3]);
        a1[4]=fmaf(w1,k1.x,a1[4]); a1[5]=fmaf(w1,k1.y,a1[5]);
        a1[6]=fmaf(w1,k1.z,a1[6]); a1[7]=fmaf(w1,k1.w,a1[7]);
      }
      __syncthreads();
    }
    #pragma unroll
    for (int t = 0; t < 8; t++){
      a0[t] += __shfl_xor(a0[t], 16); a0[t] += __shfl_xor(a0[t], 32);
      a1[t] += __shfl_xor(a1[t], 16); a1[t] += __shfl_xor(a1[t], 32);
    }
    float* part = qp_s;
    if (g2 == 1 && quad == 0){
      *(float4*)(part + (2*p2  )*HD + h0    ) = (float4){a0[0],a0[1],a0[2],a0[3]};
      *(float4*)(part + (2*p2  )*HD + h0 + 4) = (float4){a0[4],a0[5],a0[6],a0[7]};
      *(float4*)(part + (2*p2+1)*HD + h0    ) = (float4){a1[0],a1[1],a1[2],a1[3]};
      *(float4*)(part + (2*p2+1)*HD + h0 + 4) = (float4){a1[4],a1[5],a1[6],a1[7]};
    }
    __syncthreads();
    if (g2 == 0 && quad == 0){
      const float4 p00 = *(const float4*)(part + (2*p2  )*HD + h0    );
      const float4 p01 = *(const float4*)(part + (2*p2  )*HD + h0 + 4);
      const float4 p10 = *(const float4*)(part + (2*p2+1)*HD + h0    );
      const float4 p11 = *(const float4*)(part + (2*p2+1)*HD + h0 + 4);
      const size_t crow0 = (size_t)(b*TQN + qbase + 2*p2    )*HD + h0;
      const size_t crow1 = (size_t)(b*TQN + qbase + 2*p2 + 1)*HD + h0;
      if (fQ){
        float* oc = (float*)out;
        *(float4*)(oc + crow0)     = (float4){a0[0]+p00.x, a0[1]+p00.y, a0[2]+p00.z, a0[3]+p00.w};
        *(float4*)(oc + crow0 + 4) = (float4){a0[4]+p01.x, a0[5]+p01.y, a0[6]+p01.z, a0[7]+p01.w};
        *(float4*)(oc + crow1)     = (float4){a1[0]+p10.x, a1[1]+p10.y, a1[2]+p10.z, a1[3]+p10.w};
        *(float4*)(oc + crow1 + 4) = (float4){a1[4]+p11.x, a1[5]+p11.y, a1[6]+p11.z, a1[7]+p11.w};
      } else {
        uint4 o0, o1;
        o0.x = f2bf(a0[0]+p00.x) | (f2bf(a0[1]+p00.y) << 16);
        o0.y = f2bf(a0[2]+p00.z) | (f2bf(a0[3]+p00.w) << 16);
        o0.z = f2bf(a0[4]+p01.x) | (f2bf(a0[5]+p01.y) << 16);
        o0.w = f2bf(a0[6]+p01.z) | (f2bf(a0[7]+p01.w) << 16);
        o1.x = f2bf(a1[0]+p10.x) | (f2bf(a1[1]+p10.y) << 16);
        o1.y = f2bf(a1[2]+p10.z) | (f2bf(a1[3]+p10.w) << 16);
        o1.z = f2bf(a1[4]+p11.x) | (f2bf(a1[5]+p11.y) << 16);
        o1.w = f2bf(a1[6]+p11.z) | (f2bf(a1[7]+p11.w) << 16);
        *(uint4*)((unsigned short*)out + crow0) = o0;
        *(uint4*)((unsigned short*)out + crow1) = o1;
      }
    }
  }
}

extern "C" void kernel_launch(void* const* d_in, const int* in_sizes, int n_in,
                              void* d_out, int out_size, void* d_ws, size_t ws_size,
                              hipStream_t stream) {
  (void)in_sizes; (void)n_in; (void)out_size;
  const size_t need = (size_t)2 * NB * TQN * HD * sizeof(float);  // 4 MB
  if (ws_size >= need){
    float* tq_g = (float*)d_ws;
    float* tk_g = tq_g + (size_t)NB*TQN*HD;
    proj_kernel<<<512, 256, 0, stream>>>(d_in[0], d_in[1], d_in[2], d_in[3],
                                         d_in[4], d_in[5], tq_g, tk_g);
    attn_kernel<<<512, 512, 0, stream>>>(d_in[0], d_in[1], d_in[6],
                                         tq_g, tk_g, d_out);
  } else {
    fused_kernel<<<512, 512, 0, stream>>>(d_in[0], d_in[1], d_in[2], d_in[3],
                                          d_in[4], d_in[5], d_in[6], d_out);
  }
}